// Round 7
// baseline (4058.640 us; speedup 1.0000x reference)
//
#include <hip/hip_runtime.h>
#include <hip/hip_bf16.h>
#include <cstdint>
#include <cstddef>

#define B_ 4
#define T_ 2048
#define D_ 1024
#define H_ 2048

typedef __attribute__((ext_vector_type(8))) short s8v;   // 8 bf16 (4 VGPR)
typedef __attribute__((ext_vector_type(4))) float f4v;   // 4 f32 acc

__device__ __forceinline__ float bflo(unsigned int u){ union{unsigned int i;float f;}c; c.i=u<<16; return c.f; }
__device__ __forceinline__ float bfhi(unsigned int u){ union{unsigned int i;float f;}c; c.i=u&0xffff0000u; return c.f; }
__device__ __forceinline__ unsigned short f2bf(float f){
    __hip_bfloat16 h = __float2bfloat16(f);
    union { __hip_bfloat16 h; unsigned short u; } c; c.h = h; return c.u;
}
__device__ __forceinline__ unsigned int pk2(float lo, float hi){
    return (unsigned int)f2bf(lo) | ((unsigned int)f2bf(hi) << 16);
}
__device__ __forceinline__ float sigm(float x){ return 1.f/(1.f+expf(-x)); }

__device__ __forceinline__ void gload16(const void* g, void* l){
    __builtin_amdgcn_global_load_lds(
        (const __attribute__((address_space(1))) unsigned int*)g,
        (__attribute__((address_space(3))) unsigned int*)l, 16, 0, 0);
}

// ============ fp32 -> bf16 conversion, vec8 ============
__global__ __launch_bounds__(256)
void cvt8(const float* __restrict__ s, unsigned short* __restrict__ d)
{
    size_t i = ((size_t)blockIdx.x*256 + threadIdx.x)*8;
    float4 a = *(const float4*)(s+i), b = *(const float4*)(s+i+4);
    uint4 o; o.x=pk2(a.x,a.y); o.y=pk2(a.z,a.w); o.z=pk2(b.x,b.y); o.w=pk2(b.z,b.w);
    *(uint4*)(d+i)=o;
}

// ======================================================================
// m97-config MFMA GEMM: 128x128 tile, BK=32, 16KB LDS, 4 waves, target
// 8 blocks/CU (occupancy = the proven lever; m114/m97). Per K-step:
// 4 gload16 + 8 ds_read_b128 + 16 MFMA + 2 barriers.
// LDS layout per operand (8KB): 64 superrows (row pairs) x 128B; logical
// slot l=(row&1)*4+s stored at l^(rp&7) -- r6-verified 0 bank conflicts.
// Staging: linear gload_lds dest + inverse-swizzled GLOBAL source (rule 21).
// EPI 0: f32 store to Cf. EPI 1: split gate|u (bf16, plane stride H).
// EPI 2: +bias; alpha=sigmoid(-f)^ap | xin=sigm(i)*vsrc | sigm(o).
// ======================================================================
template<int EPI>
__global__ __launch_bounds__(256, 8)
void mgemm32(const unsigned short* __restrict__ A, int lda,
             const unsigned short* __restrict__ Bw, int K, int N,
             const float* __restrict__ bias,
             unsigned short* __restrict__ C0, unsigned short* __restrict__ C1,
             unsigned short* __restrict__ C2, float* __restrict__ Cf,
             const unsigned short* __restrict__ vsrc, const float* __restrict__ app)
{
    __shared__ unsigned short As[128*32];   // 8KB
    __shared__ unsigned short Bs[128*32];   // 8KB
    const int tid = threadIdx.x;
    const int lane = tid & 63;
    const int wid = tid >> 6;

    // XCD-chunked swizzle; grid = (N/128, 64), m-fastest within chunk
    const int nwg = gridDim.x * 64;
    const int orig = blockIdx.y * gridDim.x + blockIdx.x;
    const int q = nwg >> 3;
    const int wg = (orig & 7) * q + (orig >> 3);
    const int m0 = (wg & 63) * 128;
    const int n0 = (wg >> 6) * 128;

    // staging: slot si = rnd*256 + tid -> rp=si>>3, ls=si&7, l=ls^(rp&7),
    // row=2rp+(l>>2), colslot=l&3. 2 rounds x 2 operands = 4 gload16/step.
    const char* sA[2]; const char* sB[2]; int dOff[2];
#pragma unroll
    for (int r = 0; r < 2; ++r) {
        int si = r*256 + tid;
        int rp = si >> 3;
        int l  = (si & 7) ^ (rp & 7);
        int row = 2*rp + (l >> 2);
        int cs = l & 3;
        sA[r] = (const char*)(A  + (size_t)(m0+row)*lda) + cs*16;
        sB[r] = (const char*)(Bw + (size_t)(n0+row)*K)   + cs*16;
        dOff[r] = (r*256 + wid*64) * 16;   // wave-uniform; DMA adds lane*16
    }

    const int wm = wid >> 1, wn = wid & 1;
    const int fr = lane & 15, fg = lane >> 4;
    int aoff[4], boff[4];
#pragma unroll
    for (int m = 0; m < 4; ++m) {
        int row = wm*64 + m*16 + fr;
        int rp = row >> 1;
        int l = ((row & 1)*4 + fg) ^ (rp & 7);
        aoff[m] = rp*128 + l*16;
    }
#pragma unroll
    for (int n = 0; n < 4; ++n) {
        int row = wn*64 + n*16 + fr;
        int rp = row >> 1;
        int l = ((row & 1)*4 + fg) ^ (rp & 7);
        boff[n] = rp*128 + l*16;
    }
    const char* Asc = (const char*)As;
    const char* Bsc = (const char*)Bs;

    f4v acc[4][4];
#pragma unroll
    for (int m = 0; m < 4; ++m)
#pragma unroll
        for (int n = 0; n < 4; ++n) { f4v z4 = {0.f,0.f,0.f,0.f}; acc[m][n] = z4; }

    for (int k0 = 0; k0 < K; k0 += 32) {
        const size_t kb = (size_t)k0 * 2;   // byte offset along K
#pragma unroll
        for (int r = 0; r < 2; ++r) {
            gload16(sA[r] + kb, (void*)((char*)As + dOff[r]));
            gload16(sB[r] + kb, (void*)((char*)Bs + dOff[r]));
        }
        __syncthreads();
        s8v a[4], b[4];
#pragma unroll
        for (int m = 0; m < 4; ++m) a[m] = *(const s8v*)(Asc + aoff[m]);
#pragma unroll
        for (int n = 0; n < 4; ++n) b[n] = *(const s8v*)(Bsc + boff[n]);
#pragma unroll
        for (int m = 0; m < 4; ++m)
#pragma unroll
            for (int n = 0; n < 4; ++n)
                acc[m][n] = __builtin_amdgcn_mfma_f32_16x16x32_bf16(a[m], b[n], acc[m][n], 0, 0, 0);
        __syncthreads();
    }

    // ---- epilogue; C/D: col = lane&15, row = (lane>>4)*4 + j  [m89] ----
    float apv = 1.f; bool ap1 = true;
    if (EPI == 2) { apv = fmaxf(app[0], 0.f); ap1 = (apv == 1.0f); }
    const int cr = (lane >> 4) * 4;
    const int cc = lane & 15;
#pragma unroll
    for (int m = 0; m < 4; ++m) {
        const int grow0 = m0 + wm*64 + m*16 + cr;
#pragma unroll
        for (int n = 0; n < 4; ++n) {
            const int colb = n0 + wn*64 + n*16;   // wave-uniform -> plane uniform
            const int gcol = colb + cc;
            if (EPI == 0) {
#pragma unroll
                for (int j = 0; j < 4; ++j)
                    Cf[(size_t)(grow0+j)*N + gcol] = acc[m][n][j];
            } else if (EPI == 1) {
                unsigned short* dst = (colb < H_) ? C0 : C1;
                const int pc = gcol & (H_-1);
#pragma unroll
                for (int j = 0; j < 4; ++j)
                    dst[(size_t)(grow0+j)*H_ + pc] = f2bf(acc[m][n][j]);
            } else {
                const int plane = colb >> 11;
                const int pc = gcol & (H_-1);
#pragma unroll
                for (int j = 0; j < 4; ++j) {
                    float val = acc[m][n][j] + bias[gcol];
                    const size_t off = (size_t)(grow0+j)*H_ + pc;
                    if (plane == 0) {
                        float s = 1.f/(1.f+expf(val));          // sigmoid(-f)
                        C0[off] = f2bf(ap1 ? s : powf(s, apv));
                    } else if (plane == 1) {
                        C1[off] = f2bf(sigm(val) * bflo(vsrc[off]));
                    } else {
                        C2[off] = f2bf(sigm(val));
                    }
                }
            }
        }
    }
}

// ============ 128x128 BK=64 GEMM (round-3/4 proven; fallback only) ============
template<int AM, int BM, int EPI>
__global__ __launch_bounds__(256)
void mgemm(const void* __restrict__ Asrc, int lda,
           const void* __restrict__ Bsrc, int K, int N,
           const float* __restrict__ bias,
           unsigned short* __restrict__ C0, unsigned short* __restrict__ C1,
           unsigned short* __restrict__ C2, float* __restrict__ Cf,
           const unsigned short* __restrict__ vsrc, const float* __restrict__ app)
{
    __shared__ unsigned short As[128*64];
    __shared__ unsigned short Bs[128*64];
    const int tid = threadIdx.x;
    const int lane = tid & 63;
    const int wid = tid >> 6;

    const int nwg = gridDim.x * 64;
    const int orig = blockIdx.y * gridDim.x + blockIdx.x;
    const int q = nwg >> 3;
    const int wg = (orig & 7) * q + (orig >> 3);
    const int m0 = (wg & 63) * 128;
    const int n0 = (wg >> 6) * 128;

    const int ar0 = wid * 32;
    const int alr = lane >> 3;
    const int alj = lane & 7;
    const int rr = tid >> 1;
    const int kh = tid & 1;

    const int wm = wid >> 1, wn = wid & 1;
    const int fr = lane & 15, fg = lane >> 4;
    int aoff[4][2], boff[4][2];
#pragma unroll
    for (int m = 0; m < 4; ++m) {
        int row = wm*64 + m*16 + fr;
#pragma unroll
        for (int s = 0; s < 2; ++s)
            aoff[m][s] = row*128 + (((s*4 + fg) ^ (row & 7)) * 16);
    }
#pragma unroll
    for (int n = 0; n < 4; ++n) {
        int row = wn*64 + n*16 + fr;
#pragma unroll
        for (int s = 0; s < 2; ++s)
            boff[n][s] = row*128 + (((s*4 + fg) ^ (row & 7)) * 16);
    }
    const char* Asc = (const char*)As;
    const char* Bsc = (const char*)Bs;

    f4v acc[4][4];
#pragma unroll
    for (int m = 0; m < 4; ++m)
#pragma unroll
        for (int n = 0; n < 4; ++n) { f4v z4 = {0.f,0.f,0.f,0.f}; acc[m][n] = z4; }

    for (int k0 = 0; k0 < K; k0 += 64) {
        if (AM == 1) {
            const unsigned short* Ab = (const unsigned short*)Asrc;
#pragma unroll
            for (int i = 0; i < 4; ++i) {
                int row = ar0 + i*8 + alr;
                int ss = alj ^ alr;
                const char* g = (const char*)(Ab + (size_t)(m0+row)*lda + k0) + ss*16;
                gload16(g, (void*)((char*)As + (ar0 + i*8)*128));
            }
        } else {
            const float* src = (const float*)Asrc + (size_t)(m0+rr)*lda + k0 + kh*32;
            float4 v[8];
#pragma unroll
            for (int i = 0; i < 8; ++i) v[i] = ((const float4*)src)[i];
#pragma unroll
            for (int qd = 0; qd < 4; ++qd) {
                uint4 w;
                w.x = pk2(v[2*qd].x, v[2*qd].y);   w.y = pk2(v[2*qd].z, v[2*qd].w);
                w.z = pk2(v[2*qd+1].x, v[2*qd+1].y); w.w = pk2(v[2*qd+1].z, v[2*qd+1].w);
                int j = (kh*4 + qd) ^ (rr & 7);
                *(uint4*)((char*)As + rr*128 + j*16) = w;
            }
        }
        if (BM == 1) {
            const unsigned short* Bb = (const unsigned short*)Bsrc;
#pragma unroll
            for (int i = 0; i < 4; ++i) {
                int row = ar0 + i*8 + alr;
                int ss = alj ^ alr;
                const char* g = (const char*)(Bb + (size_t)(n0+row)*K + k0) + ss*16;
                gload16(g, (void*)((char*)Bs + (ar0 + i*8)*128));
            }
        } else {
            const float* src = (const float*)Bsrc + (size_t)(n0+rr)*K + k0 + kh*32;
            float4 v[8];
#pragma unroll
            for (int i = 0; i < 8; ++i) v[i] = ((const float4*)src)[i];
#pragma unroll
            for (int qd = 0; qd < 4; ++qd) {
                uint4 w;
                w.x = pk2(v[2*qd].x, v[2*qd].y);   w.y = pk2(v[2*qd].z, v[2*qd].w);
                w.z = pk2(v[2*qd+1].x, v[2*qd+1].y); w.w = pk2(v[2*qd+1].z, v[2*qd+1].w);
                int j = (kh*4 + qd) ^ (rr & 7);
                *(uint4*)((char*)Bs + rr*128 + j*16) = w;
            }
        }
        __syncthreads();
#pragma unroll
        for (int s = 0; s < 2; ++s) {
            s8v a[4], b[4];
#pragma unroll
            for (int m = 0; m < 4; ++m) a[m] = *(const s8v*)(Asc + aoff[m][s]);
#pragma unroll
            for (int n = 0; n < 4; ++n) b[n] = *(const s8v*)(Bsc + boff[n][s]);
#pragma unroll
            for (int m = 0; m < 4; ++m)
#pragma unroll
                for (int n = 0; n < 4; ++n)
                    acc[m][n] = __builtin_amdgcn_mfma_f32_16x16x32_bf16(a[m], b[n], acc[m][n], 0, 0, 0);
        }
        __syncthreads();
    }

    float apv = 1.f; bool ap1 = true;
    if (EPI == 2) { apv = fmaxf(app[0], 0.f); ap1 = (apv == 1.0f); }
    const int cr = (lane >> 4) * 4;
    const int cc = lane & 15;
#pragma unroll
    for (int m = 0; m < 4; ++m) {
        const int grow0 = m0 + wm*64 + m*16 + cr;
#pragma unroll
        for (int n = 0; n < 4; ++n) {
            const int colb = n0 + wn*64 + n*16;
            const int gcol = colb + cc;
            if (EPI == 0) {
#pragma unroll
                for (int j = 0; j < 4; ++j)
                    Cf[(size_t)(grow0+j)*N + gcol] = acc[m][n][j];
            } else if (EPI == 1) {
                unsigned short* dst = (colb < H_) ? C0 : C1;
                const int pc = gcol & (H_-1);
#pragma unroll
                for (int j = 0; j < 4; ++j)
                    dst[(size_t)(grow0+j)*H_ + pc] = f2bf(acc[m][n][j]);
            } else {
                const int plane = colb >> 11;
                const int pc = gcol & (H_-1);
#pragma unroll
                for (int j = 0; j < 4; ++j) {
                    float val = acc[m][n][j] + bias[gcol];
                    const size_t off = (size_t)(grow0+j)*H_ + pc;
                    if (plane == 0) {
                        float s = 1.f/(1.f+expf(val));
                        C0[off] = f2bf(ap1 ? s : powf(s, apv));
                    } else if (plane == 1) {
                        C1[off] = f2bf(sigm(val) * bflo(vsrc[off]));
                    } else {
                        C2[off] = f2bf(sigm(val));
                    }
                }
            }
        }
    }
}

// ============ causal depthwise conv K=4, vec8 ============
__global__ __launch_bounds__(256)
void conv8(const unsigned short* __restrict__ u, const float* __restrict__ Wc,
           const float* __restrict__ bc, unsigned short* __restrict__ v)
{
    size_t i8 = ((size_t)blockIdx.x*256 + threadIdx.x) * 8;
    int h = (int)(i8 % H_);
    size_t bt = i8 / H_;
    int t = (int)(bt % T_);
    float w[8][4], acc[8];
#pragma unroll
    for (int j = 0; j < 8; ++j) {
        float4 wr = *(const float4*)(Wc + (h+j)*4);
        w[j][0]=wr.x; w[j][1]=wr.y; w[j][2]=wr.z; w[j][3]=wr.w;
        acc[j] = bc[h+j];
    }
    const unsigned short* up = u + bt*H_ + h;
#pragma unroll
    for (int k = 0; k < 4; ++k) {
        int dt = 3 - k;
        if (t >= dt) {
            uint4 r = *(const uint4*)(up - (size_t)dt*H_);
            float e[8] = {bflo(r.x),bfhi(r.x),bflo(r.y),bfhi(r.y),
                          bflo(r.z),bfhi(r.z),bflo(r.w),bfhi(r.w)};
#pragma unroll
            for (int j = 0; j < 8; ++j) acc[j] = fmaf(e[j], w[j][k], acc[j]);
        }
    }
    uint4 o;
    o.x = pk2(acc[0],acc[1]); o.y = pk2(acc[2],acc[3]);
    o.z = pk2(acc[4],acc[5]); o.w = pk2(acc[6],acc[7]);
    *(uint4*)(v + i8) = o;
}

// ============ scan pass 1 ============
__global__ __launch_bounds__(256)
void scan_chunk8(const unsigned short* __restrict__ al, const unsigned short* __restrict__ xi,
                 float* __restrict__ cA, float* __restrict__ cB, int CT)
{
    int hh = threadIdx.x * 8;
    int c = blockIdx.y, b = blockIdx.z;
    size_t base = ((size_t)b*T_ + (size_t)c*CT)*H_ + hh;
    float A[8], Bv[8];
#pragma unroll
    for (int j=0;j<8;++j){ A[j]=1.f; Bv[j]=0.f; }
    for (int t = 0; t < CT; ++t) {
        uint4 wa = *(const uint4*)(al+base);
        uint4 wx = *(const uint4*)(xi+base);
        float a[8]={bflo(wa.x),bfhi(wa.x),bflo(wa.y),bfhi(wa.y),bflo(wa.z),bfhi(wa.z),bflo(wa.w),bfhi(wa.w)};
        float x[8]={bflo(wx.x),bfhi(wx.x),bflo(wx.y),bfhi(wx.y),bflo(wx.z),bfhi(wx.z),bflo(wx.w),bfhi(wx.w)};
#pragma unroll
        for (int j=0;j<8;++j){ A[j]*=a[j]; Bv[j]=fmaf(a[j],Bv[j],x[j]); }
        base += H_;
    }
    size_t ci = ((size_t)b*gridDim.y + c)*H_ + hh;
    *(float4*)(cA+ci)   = (float4){A[0],A[1],A[2],A[3]};
    *(float4*)(cA+ci+4) = (float4){A[4],A[5],A[6],A[7]};
    *(float4*)(cB+ci)   = (float4){Bv[0],Bv[1],Bv[2],Bv[3]};
    *(float4*)(cB+ci+4) = (float4){Bv[4],Bv[5],Bv[6],Bv[7]};
}

// ============ scan pass 2 ============
__global__ __launch_bounds__(256)
void scan_carry8(const float* __restrict__ cA, const float* __restrict__ cB,
                 float* __restrict__ cin, int NC)
{
    int gt = blockIdx.x*256 + threadIdx.x;
    int hh = (gt * 8) % H_;
    int b  = (gt * 8) / H_;
    float h[8];
#pragma unroll
    for (int j=0;j<8;++j) h[j]=0.f;
    for (int c = 0; c < NC; ++c) {
        size_t ci = ((size_t)b*NC + c)*H_ + hh;
        *(float4*)(cin+ci)   = (float4){h[0],h[1],h[2],h[3]};
        *(float4*)(cin+ci+4) = (float4){h[4],h[5],h[6],h[7]};
        float4 a0 = *(const float4*)(cA+ci), a1 = *(const float4*)(cA+ci+4);
        float4 b0 = *(const float4*)(cB+ci), b1 = *(const float4*)(cB+ci+4);
        float a[8]={a0.x,a0.y,a0.z,a0.w,a1.x,a1.y,a1.z,a1.w};
        float x[8]={b0.x,b0.y,b0.z,b0.w,b1.x,b1.y,b1.z,b1.w};
#pragma unroll
        for (int j=0;j<8;++j) h[j] = fmaf(a[j], h[j], x[j]);
    }
}

// ============ scan pass 3 ============
__global__ __launch_bounds__(256)
void scan_apply8(const unsigned short* __restrict__ al, const unsigned short* __restrict__ xi,
                 const unsigned short* __restrict__ so, const unsigned short* __restrict__ ga,
                 const float* __restrict__ cin, unsigned short* __restrict__ z, int CT)
{
    int hh = threadIdx.x * 8;
    int c = blockIdx.y, b = blockIdx.z;
    size_t base = ((size_t)b*T_ + (size_t)c*CT)*H_ + hh;
    size_t ci = ((size_t)b*gridDim.y + c)*H_ + hh;
    float h[8];
    {
        float4 h0 = *(const float4*)(cin+ci), h1 = *(const float4*)(cin+ci+4);
        h[0]=h0.x; h[1]=h0.y; h[2]=h0.z; h[3]=h0.w;
        h[4]=h1.x; h[5]=h1.y; h[6]=h1.z; h[7]=h1.w;
    }
    for (int t = 0; t < CT; ++t) {
        uint4 wa = *(const uint4*)(al+base);
        uint4 wx = *(const uint4*)(xi+base);
        uint4 ws_ = *(const uint4*)(so+base);
        uint4 wg = *(const uint4*)(ga+base);
        float a[8]={bflo(wa.x),bfhi(wa.x),bflo(wa.y),bfhi(wa.y),bflo(wa.z),bfhi(wa.z),bflo(wa.w),bfhi(wa.w)};
        float x[8]={bflo(wx.x),bfhi(wx.x),bflo(wx.y),bfhi(wx.y),bflo(wx.z),bfhi(wx.z),bflo(wx.w),bfhi(wx.w)};
        float s[8]={bflo(ws_.x),bfhi(ws_.x),bflo(ws_.y),bfhi(ws_.y),bflo(ws_.z),bfhi(ws_.z),bflo(ws_.w),bfhi(ws_.w)};
        float g[8]={bflo(wg.x),bfhi(wg.x),bflo(wg.y),bfhi(wg.y),bflo(wg.z),bfhi(wg.z),bflo(wg.w),bfhi(wg.w)};
        float zo[8];
#pragma unroll
        for (int j=0;j<8;++j) {
            h[j] = fmaf(a[j], h[j], x[j]);
            float ge = 0.5f*g[j]*(1.f+erff(g[j]*0.70710678118654752f));
            zo[j] = ge * s[j] * h[j];
        }
        uint4 o;
        o.x = pk2(zo[0],zo[1]); o.y = pk2(zo[2],zo[3]);
        o.z = pk2(zo[4],zo[5]); o.w = pk2(zo[6],zo[7]);
        *(uint4*)(z + base) = o;
        base += H_;
    }
}

__global__ void zero_out(float* __restrict__ out, size_t n)
{
    for (size_t i = (size_t)blockIdx.x*256 + threadIdx.x; i < n; i += (size_t)gridDim.x*256)
        out[i] = 0.f;
}

extern "C" void kernel_launch(void* const* d_in, const int* in_sizes, int n_in,
                              void* d_out, int out_size, void* d_ws, size_t ws_size,
                              hipStream_t stream)
{
    const float* x       = (const float*)d_in[0];
    const float* W_in    = (const float*)d_in[1];
    const float* W_conv  = (const float*)d_in[2];
    const float* b_conv  = (const float*)d_in[3];
    const float* W_gates = (const float*)d_in[4];
    const float* b_gates = (const float*)d_in[5];
    const float* W_out   = (const float*)d_in[6];
    const float* alpha_p = (const float*)d_in[7];
    float* out = (float*)d_out;

    const size_t plane = (size_t)B_ * T_ * H_;   // 16.78M elems
    unsigned short* gate = (unsigned short*)d_ws;
    unsigned short* u    = gate + plane;   // -> alpha after GEMM2
    unsigned short* v    = u + plane;      // -> z after scan
    unsigned short* xin  = v + plane;
    unsigned short* so   = xin + plane;
    char* R = (char*)(so + plane);         // time-shared region

    const size_t x_elems  = (size_t)B_*T_*D_;
    const size_t wg_elems = (size_t)3*H_*H_;
    const size_t wi_elems = (size_t)2*H_*D_;
    const size_t wo_elems = (size_t)D_*H_;
    const int NCF = 64;
    const size_t carry_b = 3*(size_t)B_*NCF*H_*4;
    const size_t Rneed = x_elems*2 > carry_b + wo_elems*2 ? x_elems*2 : carry_b + wo_elems*2;
    const size_t need_fast = 5*plane*2 + Rneed;

    if (ws_size >= need_fast && (size_t)out_size*4 >= (wg_elems + wi_elems)*2) {
        // ---------- fast path: BK=32/16KB occupancy-first GEMMs ----------
        unsigned short* wgb  = (unsigned short*)d_out;      // dead before GEMM3 writes out
        unsigned short* winb = wgb + wg_elems;
        unsigned short* xb   = (unsigned short*)R;          // live through GEMM1
        float* cAp  = (float*)R;                            // written after GEMM1
        float* cBp  = cAp + (size_t)B_*NCF*H_;
        float* cinp = cBp + (size_t)B_*NCF*H_;
        unsigned short* woutb = (unsigned short*)(cinp + (size_t)B_*NCF*H_);
        const int CT = T_ / NCF;

        cvt8<<<(unsigned)(x_elems/2048),  256, 0, stream>>>(x, xb);
        cvt8<<<(unsigned)(wi_elems/2048), 256, 0, stream>>>(W_in, winb);
        cvt8<<<(unsigned)(wg_elems/2048), 256, 0, stream>>>(W_gates, wgb);
        // GEMM1: gate|u = x @ W_in^T
        mgemm32<1><<<dim3(32,64), 256, 0, stream>>>(
            xb, D_, winb, D_, 2*H_, nullptr, gate, u, nullptr, nullptr, nullptr, nullptr);
        conv8<<<(unsigned)(plane/8/256), 256, 0, stream>>>(u, W_conv, b_conv, v);
        cvt8<<<(unsigned)(wo_elems/2048), 256, 0, stream>>>(W_out, woutb);  // xb dead
        // GEMM2: alpha|xin|so = f(v @ W_gates^T + b)
        mgemm32<2><<<dim3(48,64), 256, 0, stream>>>(
            v, H_, wgb, H_, 3*H_, b_gates, u, xin, so, nullptr, v, alpha_p);
        scan_chunk8<<<dim3(1,NCF,B_), 256, 0, stream>>>(u, xin, cAp, cBp, CT);
        scan_carry8<<<(B_*H_/8)/256, 256, 0, stream>>>(cAp, cBp, cinp, NCF);
        scan_apply8<<<dim3(1,NCF,B_), 256, 0, stream>>>(u, xin, so, gate, cinp, v, CT);
        // GEMM3: out = z @ W_out^T
        mgemm32<0><<<dim3(8,64), 256, 0, stream>>>(
            v, H_, woutb, H_, D_, nullptr, nullptr, nullptr, nullptr, out, nullptr, nullptr);
        return;
    }

    // ---------- fallback: round-3 proven path ----------
    float* cAp = (float*)R;
    int NC = 64;
    if (ws_size < 5*plane*2 + 3*(size_t)B_*64*H_*4) {
        NC = 16;
        if (ws_size < 5*plane*2 + 3*(size_t)B_*16*H_*4) {
            zero_out<<<2048, 256, 0, stream>>>(out, (size_t)out_size);
            return;
        }
    }
    const int CT = T_ / NC;
    float* cBp  = cAp + (size_t)B_*NC*H_;
    float* cinp = cBp + (size_t)B_*NC*H_;

    mgemm<0,0,1><<<dim3(32,64), 256, 0, stream>>>(
        x, D_, W_in, D_, 2*H_, nullptr, gate, u, nullptr, nullptr, nullptr, nullptr);
    conv8<<<(unsigned)(plane/8/256), 256, 0, stream>>>(u, W_conv, b_conv, v);
    mgemm<1,0,2><<<dim3(48,64), 256, 0, stream>>>(
        v, H_, W_gates, H_, 3*H_, b_gates, u, xin, so, nullptr, v, alpha_p);
    scan_chunk8<<<dim3(1,NC,B_), 256, 0, stream>>>(u, xin, cAp, cBp, CT);
    scan_carry8<<<(B_*H_/8)/256, 256, 0, stream>>>(cAp, cBp, cinp, NC);
    scan_apply8<<<dim3(1,NC,B_), 256, 0, stream>>>(u, xin, so, gate, cinp, v, CT);
    mgemm<1,0,0><<<dim3(8,64), 256, 0, stream>>>(
        v, H_, W_out, H_, D_, nullptr, nullptr, nullptr, nullptr, out, nullptr, nullptr);
}

// Round 8
// 691.799 us; speedup vs baseline: 5.8668x; 5.8668x over previous
//
#include <hip/hip_runtime.h>
#include <hip/hip_bf16.h>
#include <cstdint>
#include <cstddef>

#define B_ 4
#define T_ 2048
#define D_ 1024
#define H_ 2048

typedef __attribute__((ext_vector_type(8))) short s8v;   // 8 bf16 (4 VGPR)
typedef __attribute__((ext_vector_type(4))) float f4v;   // 4 f32 acc

__device__ __forceinline__ float bflo(unsigned int u){ union{unsigned int i;float f;}c; c.i=u<<16; return c.f; }
__device__ __forceinline__ float bfhi(unsigned int u){ union{unsigned int i;float f;}c; c.i=u&0xffff0000u; return c.f; }
__device__ __forceinline__ unsigned short f2bf(float f){
    __hip_bfloat16 h = __float2bfloat16(f);
    union { __hip_bfloat16 h; unsigned short u; } c; c.h = h; return c.u;
}
__device__ __forceinline__ unsigned int pk2(float lo, float hi){
    return (unsigned int)f2bf(lo) | ((unsigned int)f2bf(hi) << 16);
}
__device__ __forceinline__ float sigm(float x){ return 1.f/(1.f+expf(-x)); }

__device__ __forceinline__ void gload16(const void* g, void* l){
    __builtin_amdgcn_global_load_lds(
        (const __attribute__((address_space(1))) unsigned int*)g,
        (__attribute__((address_space(3))) unsigned int*)l, 16, 0, 0);
}

// ============ fp32 -> bf16 conversion, vec8 ============
__global__ __launch_bounds__(256)
void cvt8(const float* __restrict__ s, unsigned short* __restrict__ d)
{
    size_t i = ((size_t)blockIdx.x*256 + threadIdx.x)*8;
    float4 a = *(const float4*)(s+i), b = *(const float4*)(s+i+4);
    uint4 o; o.x=pk2(a.x,a.y); o.y=pk2(a.z,a.w); o.z=pk2(b.x,b.y); o.w=pk2(b.z,b.w);
    *(uint4*)(d+i)=o;
}

// ======================================================================
// m97-config MFMA GEMM: 128x128 tile, BK=32, 16KB LDS, 4 waves.
// NO min-wave clamp: r7's (256,8) forced a 64-VGPR budget -> full spill
// (VGPR_Count=32, 7.9GB scratch writes, 4x slowdown). Default bounds give
// ~160 VGPR -> 3 blocks/CU (12 waves/CU) = m97's proven operating point.
// Per K-step: 4 gload16 + 8 ds_read_b128 + 16 MFMA + 2 barriers.
// LDS layout per operand (8KB): 64 row-pairs x 128B; logical slot
// l=(row&1)*4+s stored at l^(rp&7) -- r6/r7-verified 0 bank conflicts.
// Staging: linear gload_lds dest + inverse-swizzled GLOBAL source (rule 21).
// EPI 0: f32 store to Cf. EPI 1: split gate|u (bf16, plane stride H).
// EPI 2: +bias; alpha=sigmoid(-f)^ap | xin=sigm(i)*vsrc | sigm(o).
// ======================================================================
template<int EPI>
__global__ __launch_bounds__(256)
void mgemm32(const unsigned short* __restrict__ A, int lda,
             const unsigned short* __restrict__ Bw, int K, int N,
             const float* __restrict__ bias,
             unsigned short* __restrict__ C0, unsigned short* __restrict__ C1,
             unsigned short* __restrict__ C2, float* __restrict__ Cf,
             const unsigned short* __restrict__ vsrc, const float* __restrict__ app)
{
    __shared__ unsigned short As[128*32];   // 8KB
    __shared__ unsigned short Bs[128*32];   // 8KB
    const int tid = threadIdx.x;
    const int lane = tid & 63;
    const int wid = tid >> 6;

    // XCD-chunked swizzle; grid = (N/128, 64), m-fastest within chunk
    const int nwg = gridDim.x * 64;
    const int orig = blockIdx.y * gridDim.x + blockIdx.x;
    const int q = nwg >> 3;
    const int wg = (orig & 7) * q + (orig >> 3);
    const int m0 = (wg & 63) * 128;
    const int n0 = (wg >> 6) * 128;

    // staging: slot si = rnd*256 + tid -> rp=si>>3, ls=si&7, l=ls^(rp&7),
    // row=2rp+(l>>2), colslot=l&3. 2 rounds x 2 operands = 4 gload16/step.
    const char* sA[2]; const char* sB[2]; int dOff[2];
#pragma unroll
    for (int r = 0; r < 2; ++r) {
        int si = r*256 + tid;
        int rp = si >> 3;
        int l  = (si & 7) ^ (rp & 7);
        int row = 2*rp + (l >> 2);
        int cs = l & 3;
        sA[r] = (const char*)(A  + (size_t)(m0+row)*lda) + cs*16;
        sB[r] = (const char*)(Bw + (size_t)(n0+row)*K)   + cs*16;
        dOff[r] = (r*256 + wid*64) * 16;   // wave-uniform; DMA adds lane*16
    }

    const int wm = wid >> 1, wn = wid & 1;
    const int fr = lane & 15, fg = lane >> 4;
    int aoff[4], boff[4];
#pragma unroll
    for (int m = 0; m < 4; ++m) {
        int row = wm*64 + m*16 + fr;
        int rp = row >> 1;
        int l = ((row & 1)*4 + fg) ^ (rp & 7);
        aoff[m] = rp*128 + l*16;
    }
#pragma unroll
    for (int n = 0; n < 4; ++n) {
        int row = wn*64 + n*16 + fr;
        int rp = row >> 1;
        int l = ((row & 1)*4 + fg) ^ (rp & 7);
        boff[n] = rp*128 + l*16;
    }
    const char* Asc = (const char*)As;
    const char* Bsc = (const char*)Bs;

    f4v acc[4][4];
#pragma unroll
    for (int m = 0; m < 4; ++m)
#pragma unroll
        for (int n = 0; n < 4; ++n) { f4v z4 = {0.f,0.f,0.f,0.f}; acc[m][n] = z4; }

    for (int k0 = 0; k0 < K; k0 += 32) {
        const size_t kb = (size_t)k0 * 2;   // byte offset along K
#pragma unroll
        for (int r = 0; r < 2; ++r) {
            gload16(sA[r] + kb, (void*)((char*)As + dOff[r]));
            gload16(sB[r] + kb, (void*)((char*)Bs + dOff[r]));
        }
        __syncthreads();
        s8v a[4], b[4];
#pragma unroll
        for (int m = 0; m < 4; ++m) a[m] = *(const s8v*)(Asc + aoff[m]);
#pragma unroll
        for (int n = 0; n < 4; ++n) b[n] = *(const s8v*)(Bsc + boff[n]);
#pragma unroll
        for (int m = 0; m < 4; ++m)
#pragma unroll
            for (int n = 0; n < 4; ++n)
                acc[m][n] = __builtin_amdgcn_mfma_f32_16x16x32_bf16(a[m], b[n], acc[m][n], 0, 0, 0);
        __syncthreads();
    }

    // ---- epilogue; C/D: col = lane&15, row = (lane>>4)*4 + j  [m89] ----
    float apv = 1.f; bool ap1 = true;
    if (EPI == 2) { apv = fmaxf(app[0], 0.f); ap1 = (apv == 1.0f); }
    const int cr = (lane >> 4) * 4;
    const int cc = lane & 15;
#pragma unroll
    for (int m = 0; m < 4; ++m) {
        const int grow0 = m0 + wm*64 + m*16 + cr;
#pragma unroll
        for (int n = 0; n < 4; ++n) {
            const int colb = n0 + wn*64 + n*16;   // wave-uniform -> plane uniform
            const int gcol = colb + cc;
            if (EPI == 0) {
#pragma unroll
                for (int j = 0; j < 4; ++j)
                    Cf[(size_t)(grow0+j)*N + gcol] = acc[m][n][j];
            } else if (EPI == 1) {
                unsigned short* dst = (colb < H_) ? C0 : C1;
                const int pc = gcol & (H_-1);
#pragma unroll
                for (int j = 0; j < 4; ++j)
                    dst[(size_t)(grow0+j)*H_ + pc] = f2bf(acc[m][n][j]);
            } else {
                const int plane = colb >> 11;
                const int pc = gcol & (H_-1);
#pragma unroll
                for (int j = 0; j < 4; ++j) {
                    float val = acc[m][n][j] + bias[gcol];
                    const size_t off = (size_t)(grow0+j)*H_ + pc;
                    if (plane == 0) {
                        float s = 1.f/(1.f+expf(val));          // sigmoid(-f)
                        C0[off] = f2bf(ap1 ? s : powf(s, apv));
                    } else if (plane == 1) {
                        C1[off] = f2bf(sigm(val) * bflo(vsrc[off]));
                    } else {
                        C2[off] = f2bf(sigm(val));
                    }
                }
            }
        }
    }
}

// ============ 128x128 BK=64 GEMM (round-3/4 proven; fallback only) ============
template<int AM, int BM, int EPI>
__global__ __launch_bounds__(256)
void mgemm(const void* __restrict__ Asrc, int lda,
           const void* __restrict__ Bsrc, int K, int N,
           const float* __restrict__ bias,
           unsigned short* __restrict__ C0, unsigned short* __restrict__ C1,
           unsigned short* __restrict__ C2, float* __restrict__ Cf,
           const unsigned short* __restrict__ vsrc, const float* __restrict__ app)
{
    __shared__ unsigned short As[128*64];
    __shared__ unsigned short Bs[128*64];
    const int tid = threadIdx.x;
    const int lane = tid & 63;
    const int wid = tid >> 6;

    const int nwg = gridDim.x * 64;
    const int orig = blockIdx.y * gridDim.x + blockIdx.x;
    const int q = nwg >> 3;
    const int wg = (orig & 7) * q + (orig >> 3);
    const int m0 = (wg & 63) * 128;
    const int n0 = (wg >> 6) * 128;

    const int ar0 = wid * 32;
    const int alr = lane >> 3;
    const int alj = lane & 7;
    const int rr = tid >> 1;
    const int kh = tid & 1;

    const int wm = wid >> 1, wn = wid & 1;
    const int fr = lane & 15, fg = lane >> 4;
    int aoff[4][2], boff[4][2];
#pragma unroll
    for (int m = 0; m < 4; ++m) {
        int row = wm*64 + m*16 + fr;
#pragma unroll
        for (int s = 0; s < 2; ++s)
            aoff[m][s] = row*128 + (((s*4 + fg) ^ (row & 7)) * 16);
    }
#pragma unroll
    for (int n = 0; n < 4; ++n) {
        int row = wn*64 + n*16 + fr;
#pragma unroll
        for (int s = 0; s < 2; ++s)
            boff[n][s] = row*128 + (((s*4 + fg) ^ (row & 7)) * 16);
    }
    const char* Asc = (const char*)As;
    const char* Bsc = (const char*)Bs;

    f4v acc[4][4];
#pragma unroll
    for (int m = 0; m < 4; ++m)
#pragma unroll
        for (int n = 0; n < 4; ++n) { f4v z4 = {0.f,0.f,0.f,0.f}; acc[m][n] = z4; }

    for (int k0 = 0; k0 < K; k0 += 64) {
        if (AM == 1) {
            const unsigned short* Ab = (const unsigned short*)Asrc;
#pragma unroll
            for (int i = 0; i < 4; ++i) {
                int row = ar0 + i*8 + alr;
                int ss = alj ^ alr;
                const char* g = (const char*)(Ab + (size_t)(m0+row)*lda + k0) + ss*16;
                gload16(g, (void*)((char*)As + (ar0 + i*8)*128));
            }
        } else {
            const float* src = (const float*)Asrc + (size_t)(m0+rr)*lda + k0 + kh*32;
            float4 v[8];
#pragma unroll
            for (int i = 0; i < 8; ++i) v[i] = ((const float4*)src)[i];
#pragma unroll
            for (int qd = 0; qd < 4; ++qd) {
                uint4 w;
                w.x = pk2(v[2*qd].x, v[2*qd].y);   w.y = pk2(v[2*qd].z, v[2*qd].w);
                w.z = pk2(v[2*qd+1].x, v[2*qd+1].y); w.w = pk2(v[2*qd+1].z, v[2*qd+1].w);
                int j = (kh*4 + qd) ^ (rr & 7);
                *(uint4*)((char*)As + rr*128 + j*16) = w;
            }
        }
        if (BM == 1) {
            const unsigned short* Bb = (const unsigned short*)Bsrc;
#pragma unroll
            for (int i = 0; i < 4; ++i) {
                int row = ar0 + i*8 + alr;
                int ss = alj ^ alr;
                const char* g = (const char*)(Bb + (size_t)(n0+row)*K + k0) + ss*16;
                gload16(g, (void*)((char*)Bs + (ar0 + i*8)*128));
            }
        } else {
            const float* src = (const float*)Bsrc + (size_t)(n0+rr)*K + k0 + kh*32;
            float4 v[8];
#pragma unroll
            for (int i = 0; i < 8; ++i) v[i] = ((const float4*)src)[i];
#pragma unroll
            for (int qd = 0; qd < 4; ++qd) {
                uint4 w;
                w.x = pk2(v[2*qd].x, v[2*qd].y);   w.y = pk2(v[2*qd].z, v[2*qd].w);
                w.z = pk2(v[2*qd+1].x, v[2*qd+1].y); w.w = pk2(v[2*qd+1].z, v[2*qd+1].w);
                int j = (kh*4 + qd) ^ (rr & 7);
                *(uint4*)((char*)Bs + rr*128 + j*16) = w;
            }
        }
        __syncthreads();
#pragma unroll
        for (int s = 0; s < 2; ++s) {
            s8v a[4], b[4];
#pragma unroll
            for (int m = 0; m < 4; ++m) a[m] = *(const s8v*)(Asc + aoff[m][s]);
#pragma unroll
            for (int n = 0; n < 4; ++n) b[n] = *(const s8v*)(Bsc + boff[n][s]);
#pragma unroll
            for (int m = 0; m < 4; ++m)
#pragma unroll
                for (int n = 0; n < 4; ++n)
                    acc[m][n] = __builtin_amdgcn_mfma_f32_16x16x32_bf16(a[m], b[n], acc[m][n], 0, 0, 0);
        }
        __syncthreads();
    }

    float apv = 1.f; bool ap1 = true;
    if (EPI == 2) { apv = fmaxf(app[0], 0.f); ap1 = (apv == 1.0f); }
    const int cr = (lane >> 4) * 4;
    const int cc = lane & 15;
#pragma unroll
    for (int m = 0; m < 4; ++m) {
        const int grow0 = m0 + wm*64 + m*16 + cr;
#pragma unroll
        for (int n = 0; n < 4; ++n) {
            const int colb = n0 + wn*64 + n*16;
            const int gcol = colb + cc;
            if (EPI == 0) {
#pragma unroll
                for (int j = 0; j < 4; ++j)
                    Cf[(size_t)(grow0+j)*N + gcol] = acc[m][n][j];
            } else if (EPI == 1) {
                unsigned short* dst = (colb < H_) ? C0 : C1;
                const int pc = gcol & (H_-1);
#pragma unroll
                for (int j = 0; j < 4; ++j)
                    dst[(size_t)(grow0+j)*H_ + pc] = f2bf(acc[m][n][j]);
            } else {
                const int plane = colb >> 11;
                const int pc = gcol & (H_-1);
#pragma unroll
                for (int j = 0; j < 4; ++j) {
                    float val = acc[m][n][j] + bias[gcol];
                    const size_t off = (size_t)(grow0+j)*H_ + pc;
                    if (plane == 0) {
                        float s = 1.f/(1.f+expf(val));
                        C0[off] = f2bf(ap1 ? s : powf(s, apv));
                    } else if (plane == 1) {
                        C1[off] = f2bf(sigm(val) * bflo(vsrc[off]));
                    } else {
                        C2[off] = f2bf(sigm(val));
                    }
                }
            }
        }
    }
}

// ============ causal depthwise conv K=4, vec8 ============
__global__ __launch_bounds__(256)
void conv8(const unsigned short* __restrict__ u, const float* __restrict__ Wc,
           const float* __restrict__ bc, unsigned short* __restrict__ v)
{
    size_t i8 = ((size_t)blockIdx.x*256 + threadIdx.x) * 8;
    int h = (int)(i8 % H_);
    size_t bt = i8 / H_;
    int t = (int)(bt % T_);
    float w[8][4], acc[8];
#pragma unroll
    for (int j = 0; j < 8; ++j) {
        float4 wr = *(const float4*)(Wc + (h+j)*4);
        w[j][0]=wr.x; w[j][1]=wr.y; w[j][2]=wr.z; w[j][3]=wr.w;
        acc[j] = bc[h+j];
    }
    const unsigned short* up = u + bt*H_ + h;
#pragma unroll
    for (int k = 0; k < 4; ++k) {
        int dt = 3 - k;
        if (t >= dt) {
            uint4 r = *(const uint4*)(up - (size_t)dt*H_);
            float e[8] = {bflo(r.x),bfhi(r.x),bflo(r.y),bfhi(r.y),
                          bflo(r.z),bfhi(r.z),bflo(r.w),bfhi(r.w)};
#pragma unroll
            for (int j = 0; j < 8; ++j) acc[j] = fmaf(e[j], w[j][k], acc[j]);
        }
    }
    uint4 o;
    o.x = pk2(acc[0],acc[1]); o.y = pk2(acc[2],acc[3]);
    o.z = pk2(acc[4],acc[5]); o.w = pk2(acc[6],acc[7]);
    *(uint4*)(v + i8) = o;
}

// ============ scan pass 1 ============
__global__ __launch_bounds__(256)
void scan_chunk8(const unsigned short* __restrict__ al, const unsigned short* __restrict__ xi,
                 float* __restrict__ cA, float* __restrict__ cB, int CT)
{
    int hh = threadIdx.x * 8;
    int c = blockIdx.y, b = blockIdx.z;
    size_t base = ((size_t)b*T_ + (size_t)c*CT)*H_ + hh;
    float A[8], Bv[8];
#pragma unroll
    for (int j=0;j<8;++j){ A[j]=1.f; Bv[j]=0.f; }
    for (int t = 0; t < CT; ++t) {
        uint4 wa = *(const uint4*)(al+base);
        uint4 wx = *(const uint4*)(xi+base);
        float a[8]={bflo(wa.x),bfhi(wa.x),bflo(wa.y),bfhi(wa.y),bflo(wa.z),bfhi(wa.z),bflo(wa.w),bfhi(wa.w)};
        float x[8]={bflo(wx.x),bfhi(wx.x),bflo(wx.y),bfhi(wx.y),bflo(wx.z),bfhi(wx.z),bflo(wx.w),bfhi(wx.w)};
#pragma unroll
        for (int j=0;j<8;++j){ A[j]*=a[j]; Bv[j]=fmaf(a[j],Bv[j],x[j]); }
        base += H_;
    }
    size_t ci = ((size_t)b*gridDim.y + c)*H_ + hh;
    *(float4*)(cA+ci)   = (float4){A[0],A[1],A[2],A[3]};
    *(float4*)(cA+ci+4) = (float4){A[4],A[5],A[6],A[7]};
    *(float4*)(cB+ci)   = (float4){Bv[0],Bv[1],Bv[2],Bv[3]};
    *(float4*)(cB+ci+4) = (float4){Bv[4],Bv[5],Bv[6],Bv[7]};
}

// ============ scan pass 2 ============
__global__ __launch_bounds__(256)
void scan_carry8(const float* __restrict__ cA, const float* __restrict__ cB,
                 float* __restrict__ cin, int NC)
{
    int gt = blockIdx.x*256 + threadIdx.x;
    int hh = (gt * 8) % H_;
    int b  = (gt * 8) / H_;
    float h[8];
#pragma unroll
    for (int j=0;j<8;++j) h[j]=0.f;
    for (int c = 0; c < NC; ++c) {
        size_t ci = ((size_t)b*NC + c)*H_ + hh;
        *(float4*)(cin+ci)   = (float4){h[0],h[1],h[2],h[3]};
        *(float4*)(cin+ci+4) = (float4){h[4],h[5],h[6],h[7]};
        float4 a0 = *(const float4*)(cA+ci), a1 = *(const float4*)(cA+ci+4);
        float4 b0 = *(const float4*)(cB+ci), b1 = *(const float4*)(cB+ci+4);
        float a[8]={a0.x,a0.y,a0.z,a0.w,a1.x,a1.y,a1.z,a1.w};
        float x[8]={b0.x,b0.y,b0.z,b0.w,b1.x,b1.y,b1.z,b1.w};
#pragma unroll
        for (int j=0;j<8;++j) h[j] = fmaf(a[j], h[j], x[j]);
    }
}

// ============ scan pass 3 ============
__global__ __launch_bounds__(256)
void scan_apply8(const unsigned short* __restrict__ al, const unsigned short* __restrict__ xi,
                 const unsigned short* __restrict__ so, const unsigned short* __restrict__ ga,
                 const float* __restrict__ cin, unsigned short* __restrict__ z, int CT)
{
    int hh = threadIdx.x * 8;
    int c = blockIdx.y, b = blockIdx.z;
    size_t base = ((size_t)b*T_ + (size_t)c*CT)*H_ + hh;
    size_t ci = ((size_t)b*gridDim.y + c)*H_ + hh;
    float h[8];
    {
        float4 h0 = *(const float4*)(cin+ci), h1 = *(const float4*)(cin+ci+4);
        h[0]=h0.x; h[1]=h0.y; h[2]=h0.z; h[3]=h0.w;
        h[4]=h1.x; h[5]=h1.y; h[6]=h1.z; h[7]=h1.w;
    }
    for (int t = 0; t < CT; ++t) {
        uint4 wa = *(const uint4*)(al+base);
        uint4 wx = *(const uint4*)(xi+base);
        uint4 ws_ = *(const uint4*)(so+base);
        uint4 wg = *(const uint4*)(ga+base);
        float a[8]={bflo(wa.x),bfhi(wa.x),bflo(wa.y),bfhi(wa.y),bflo(wa.z),bfhi(wa.z),bflo(wa.w),bfhi(wa.w)};
        float x[8]={bflo(wx.x),bfhi(wx.x),bflo(wx.y),bfhi(wx.y),bflo(wx.z),bfhi(wx.z),bflo(wx.w),bfhi(wx.w)};
        float s[8]={bflo(ws_.x),bfhi(ws_.x),bflo(ws_.y),bfhi(ws_.y),bflo(ws_.z),bfhi(ws_.z),bflo(ws_.w),bfhi(ws_.w)};
        float g[8]={bflo(wg.x),bfhi(wg.x),bflo(wg.y),bfhi(wg.y),bflo(wg.z),bfhi(wg.z),bflo(wg.w),bfhi(wg.w)};
        float zo[8];
#pragma unroll
        for (int j=0;j<8;++j) {
            h[j] = fmaf(a[j], h[j], x[j]);
            float ge = 0.5f*g[j]*(1.f+erff(g[j]*0.70710678118654752f));
            zo[j] = ge * s[j] * h[j];
        }
        uint4 o;
        o.x = pk2(zo[0],zo[1]); o.y = pk2(zo[2],zo[3]);
        o.z = pk2(zo[4],zo[5]); o.w = pk2(zo[6],zo[7]);
        *(uint4*)(z + base) = o;
        base += H_;
    }
}

__global__ void zero_out(float* __restrict__ out, size_t n)
{
    for (size_t i = (size_t)blockIdx.x*256 + threadIdx.x; i < n; i += (size_t)gridDim.x*256)
        out[i] = 0.f;
}

extern "C" void kernel_launch(void* const* d_in, const int* in_sizes, int n_in,
                              void* d_out, int out_size, void* d_ws, size_t ws_size,
                              hipStream_t stream)
{
    const float* x       = (const float*)d_in[0];
    const float* W_in    = (const float*)d_in[1];
    const float* W_conv  = (const float*)d_in[2];
    const float* b_conv  = (const float*)d_in[3];
    const float* W_gates = (const float*)d_in[4];
    const float* b_gates = (const float*)d_in[5];
    const float* W_out   = (const float*)d_in[6];
    const float* alpha_p = (const float*)d_in[7];
    float* out = (float*)d_out;

    const size_t plane = (size_t)B_ * T_ * H_;   // 16.78M elems
    unsigned short* gate = (unsigned short*)d_ws;
    unsigned short* u    = gate + plane;   // -> alpha after GEMM2
    unsigned short* v    = u + plane;      // -> z after scan
    unsigned short* xin  = v + plane;
    unsigned short* so   = xin + plane;
    char* R = (char*)(so + plane);         // time-shared region

    const size_t x_elems  = (size_t)B_*T_*D_;
    const size_t wg_elems = (size_t)3*H_*H_;
    const size_t wi_elems = (size_t)2*H_*D_;
    const size_t wo_elems = (size_t)D_*H_;
    const int NCF = 64;
    const size_t carry_b = 3*(size_t)B_*NCF*H_*4;
    const size_t Rneed = x_elems*2 > carry_b + wo_elems*2 ? x_elems*2 : carry_b + wo_elems*2;
    const size_t need_fast = 5*plane*2 + Rneed;

    if (ws_size >= need_fast && (size_t)out_size*4 >= (wg_elems + wi_elems)*2) {
        // ---------- fast path: BK=32/16KB, default-bounds GEMMs ----------
        unsigned short* wgb  = (unsigned short*)d_out;      // dead before GEMM3 writes out
        unsigned short* winb = wgb + wg_elems;
        unsigned short* xb   = (unsigned short*)R;          // live through GEMM1
        float* cAp  = (float*)R;                            // written after GEMM1
        float* cBp  = cAp + (size_t)B_*NCF*H_;
        float* cinp = cBp + (size_t)B_*NCF*H_;
        unsigned short* woutb = (unsigned short*)(cinp + (size_t)B_*NCF*H_);
        const int CT = T_ / NCF;

        cvt8<<<(unsigned)(x_elems/2048),  256, 0, stream>>>(x, xb);
        cvt8<<<(unsigned)(wi_elems/2048), 256, 0, stream>>>(W_in, winb);
        cvt8<<<(unsigned)(wg_elems/2048), 256, 0, stream>>>(W_gates, wgb);
        // GEMM1: gate|u = x @ W_in^T
        mgemm32<1><<<dim3(32,64), 256, 0, stream>>>(
            xb, D_, winb, D_, 2*H_, nullptr, gate, u, nullptr, nullptr, nullptr, nullptr);
        conv8<<<(unsigned)(plane/8/256), 256, 0, stream>>>(u, W_conv, b_conv, v);
        cvt8<<<(unsigned)(wo_elems/2048), 256, 0, stream>>>(W_out, woutb);  // xb dead
        // GEMM2: alpha|xin|so = f(v @ W_gates^T + b)
        mgemm32<2><<<dim3(48,64), 256, 0, stream>>>(
            v, H_, wgb, H_, 3*H_, b_gates, u, xin, so, nullptr, v, alpha_p);
        scan_chunk8<<<dim3(1,NCF,B_), 256, 0, stream>>>(u, xin, cAp, cBp, CT);
        scan_carry8<<<(B_*H_/8)/256, 256, 0, stream>>>(cAp, cBp, cinp, NCF);
        scan_apply8<<<dim3(1,NCF,B_), 256, 0, stream>>>(u, xin, so, gate, cinp, v, CT);
        // GEMM3: out = z @ W_out^T
        mgemm32<0><<<dim3(8,64), 256, 0, stream>>>(
            v, H_, woutb, H_, D_, nullptr, nullptr, nullptr, nullptr, out, nullptr, nullptr);
        return;
    }

    // ---------- fallback: round-3 proven path ----------
    float* cAp = (float*)R;
    int NC = 64;
    if (ws_size < 5*plane*2 + 3*(size_t)B_*64*H_*4) {
        NC = 16;
        if (ws_size < 5*plane*2 + 3*(size_t)B_*16*H_*4) {
            zero_out<<<2048, 256, 0, stream>>>(out, (size_t)out_size);
            return;
        }
    }
    const int CT = T_ / NC;
    float* cBp  = cAp + (size_t)B_*NC*H_;
    float* cinp = cBp + (size_t)B_*NC*H_;

    mgemm<0,0,1><<<dim3(32,64), 256, 0, stream>>>(
        x, D_, W_in, D_, 2*H_, nullptr, gate, u, nullptr, nullptr, nullptr, nullptr);
    conv8<<<(unsigned)(plane/8/256), 256, 0, stream>>>(u, W_conv, b_conv, v);
    mgemm<1,0,2><<<dim3(48,64), 256, 0, stream>>>(
        v, H_, W_gates, H_, 3*H_, b_gates, u, xin, so, nullptr, v, alpha_p);
    scan_chunk8<<<dim3(1,NC,B_), 256, 0, stream>>>(u, xin, cAp, cBp, CT);
    scan_carry8<<<(B_*H_/8)/256, 256, 0, stream>>>(cAp, cBp, cinp, NC);
    scan_apply8<<<dim3(1,NC,B_), 256, 0, stream>>>(u, xin, so, gate, cinp, v, CT);
    mgemm<1,0,0><<<dim3(8,64), 256, 0, stream>>>(
        v, H_, W_out, H_, D_, nullptr, nullptr, nullptr, nullptr, out, nullptr, nullptr);
}

// Round 9
// 647.411 us; speedup vs baseline: 6.2690x; 1.0686x over previous
//
#include <hip/hip_runtime.h>
#include <hip/hip_bf16.h>
#include <cstdint>
#include <cstddef>

#define B_ 4
#define T_ 2048
#define D_ 1024
#define H_ 2048

typedef __attribute__((ext_vector_type(8))) short s8v;   // 8 bf16 (4 VGPR)
typedef __attribute__((ext_vector_type(4))) float f4v;   // 4 f32 acc

__device__ __forceinline__ float bflo(unsigned int u){ union{unsigned int i;float f;}c; c.i=u<<16; return c.f; }
__device__ __forceinline__ float bfhi(unsigned int u){ union{unsigned int i;float f;}c; c.i=u&0xffff0000u; return c.f; }
__device__ __forceinline__ unsigned short f2bf(float f){
    __hip_bfloat16 h = __float2bfloat16(f);
    union { __hip_bfloat16 h; unsigned short u; } c; c.h = h; return c.u;
}
__device__ __forceinline__ unsigned int pk2(float lo, float hi){
    return (unsigned int)f2bf(lo) | ((unsigned int)f2bf(hi) << 16);
}
__device__ __forceinline__ float sigm(float x){ return 1.f/(1.f+expf(-x)); }

__device__ __forceinline__ void gload16(const void* g, void* l){
    __builtin_amdgcn_global_load_lds(
        (const __attribute__((address_space(1))) unsigned int*)g,
        (__attribute__((address_space(3))) unsigned int*)l, 16, 0, 0);
}

// ============ fp32 -> bf16 conversion, vec8 ============
__global__ __launch_bounds__(256)
void cvt8(const float* __restrict__ s, unsigned short* __restrict__ d)
{
    size_t i = ((size_t)blockIdx.x*256 + threadIdx.x)*8;
    float4 a = *(const float4*)(s+i), b = *(const float4*)(s+i+4);
    uint4 o; o.x=pk2(a.x,a.y); o.y=pk2(a.z,a.w); o.z=pk2(b.x,b.y); o.w=pk2(b.z,b.w);
    *(uint4*)(d+i)=o;
}

// ======================================================================
// 4-phase counted-vmcnt 256x256 GEMM, BK=64, 8 waves (2Mx4N), 2 LDS bufs
// x 4 slices {A-ks0, A-ks1, B-ks0, B-ks1} x 16KB = 128KB.
// Phase (ks,mh): {ds_read 4 A-frags (+4 B-frags if mh==0); issue ONE 2-load
// stage unit for tile t+1; barrier; setprio(1); 16 MFMA; setprio(0);
// [vmcnt]; barrier}. Stage unit order per tile: A0,B0,A1,B1.
// WAIT LEDGER (per-thread loads, 2/unit): end-of-ph1 outstanding =
// {A1(t),B1(t),A0(t+1),B0(t+1)}=8 -> vmcnt(4) drains A1(t),B1(t) (read at
// ph2). End-of-ph3 outstanding = 4 units of t+1 = 8 -> vmcnt(4) drains
// A0(t+1),B0(t+1) (read at next ph0). vmcnt NEVER 0 in main loop; peeled
// last tile uses vmcnt(0) at ph1. Buffer safety: DMA into buf[(t+1)&1]
// issues after the end-of-(t-1) barrier; tile t-1's ds_reads retired
// before it (lgkm before its MFMAs). Slice layout = r8's paired-row
// slot-XOR (HW-verified 0 bank conflicts); linear DMA dest + inverse-
// swizzled global source (rule 21).
// EPI 1: N=4096 split gate|u. EPI 2: N=6144 +bias, alpha|xin|so.
// ======================================================================
template<int EPI>
__global__ __launch_bounds__(512)
void pgemm8(const unsigned short* __restrict__ A, int lda,
            const unsigned short* __restrict__ Bw, int K, int N,
            const float* __restrict__ bias,
            unsigned short* __restrict__ C0, unsigned short* __restrict__ C1,
            unsigned short* __restrict__ C2,
            const unsigned short* __restrict__ vsrc, const float* __restrict__ app)
{
    __shared__ unsigned short lds[2][4][8192];   // [buf][a0,a1,b0,b1][16KB]
    const int tid = threadIdx.x;
    const int lane = tid & 63;
    const int wid = tid >> 6;     // 0..7
    const int wm = wid >> 2;      // 0..1
    const int wn = wid & 3;       // 0..3

    // XCD-chunked swizzle (nwg % 8 == 0 for all our shapes)
    const int nwg = (N >> 8) * 32;
    const int orig = blockIdx.x;
    const int q = nwg >> 3;
    const int wg = (orig & 7) * q + (orig >> 3);
    const int m0 = (wg & 31) * 256;
    const int n0 = (wg >> 5) * 256;

    // ---- staging geometry: per slice 1024 16B slots, 2 per thread ----
    // si -> rp=si>>3, l=(si&7)^(rp&7), row=2rp+(l>>2), colslot=l&3
    const char* sA[2]; const char* sB[2]; int dOff[2];
#pragma unroll
    for (int r = 0; r < 2; ++r) {
        int si = r*512 + tid;
        int rp = si >> 3;
        int l  = (si & 7) ^ (rp & 7);
        int row = 2*rp + (l >> 2);
        int cs = l & 3;
        sA[r] = (const char*)(A  + (size_t)(m0+row)*lda) + cs*16;
        sB[r] = (const char*)(Bw + (size_t)(n0+row)*K)   + cs*16;
        dOff[r] = (r*512 + wid*64) * 16;   // wave-uniform; DMA adds lane*16
    }

    // ---- fragment ds_read byte offsets (within a slice) ----
    const int fr = lane & 15, fg = lane >> 4;
    int aoff[8], boff[4];
#pragma unroll
    for (int m = 0; m < 8; ++m) {
        int row = wm*128 + m*16 + fr;
        int rp = row >> 1;
        int l = ((row & 1)*4 + fg) ^ (rp & 7);
        aoff[m] = rp*128 + l*16;
    }
#pragma unroll
    for (int n = 0; n < 4; ++n) {
        int row = wn*64 + n*16 + fr;
        int rp = row >> 1;
        int l = ((row & 1)*4 + fg) ^ (rp & 7);
        boff[n] = rp*128 + l*16;
    }

    f4v acc[8][4];
#pragma unroll
    for (int m = 0; m < 8; ++m)
#pragma unroll
        for (int n = 0; n < 4; ++n) { f4v z4 = {0.f,0.f,0.f,0.f}; acc[m][n] = z4; }

    const int NT = K >> 6;

    // stage one unit u (0=A0,1=B0,2=A1,3=B1) of K-tile tt into buf[tt&1]
    auto stage_unit = [&](int tt, int u) {
        const int op = u & 1, ku = u >> 1;
        char* dst = (char*)&lds[tt & 1][op*2 + ku][0];
        const size_t kb = (size_t)tt*128 + (size_t)ku*64;
#pragma unroll
        for (int r = 0; r < 2; ++r)
            gload16((op ? sB[r] : sA[r]) + kb, dst + dOff[r]);
    };

    // prologue: all 4 units of tile 0 (order A0,B0,A1,B1); drain A0,B0
    stage_unit(0,0); stage_unit(0,1); stage_unit(0,2); stage_unit(0,3);
    asm volatile("s_waitcnt vmcnt(4)" ::: "memory");
    __builtin_amdgcn_s_barrier();
    __builtin_amdgcn_sched_barrier(0);

    auto tile = [&](int t, bool more) {
        const int cur = t & 1;
        s8v b[4];
#pragma unroll
        for (int ph = 0; ph < 4; ++ph) {
            const int ks = ph >> 1, mh = ph & 1;
            const char* abase = (const char*)&lds[cur][ks][0];
            const char* bbase = (const char*)&lds[cur][2 + ks][0];
            s8v a[4];
#pragma unroll
            for (int i = 0; i < 4; ++i) a[i] = *(const s8v*)(abase + aoff[mh*4 + i]);
            if (mh == 0) {
#pragma unroll
                for (int j = 0; j < 4; ++j) b[j] = *(const s8v*)(bbase + boff[j]);
            }
            if (more) stage_unit(t + 1, ph);
            __builtin_amdgcn_s_barrier();
            __builtin_amdgcn_sched_barrier(0);
            __builtin_amdgcn_s_setprio(1);
#pragma unroll
            for (int i = 0; i < 4; ++i)
#pragma unroll
                for (int j = 0; j < 4; ++j)
                    acc[mh*4+i][j] = __builtin_amdgcn_mfma_f32_16x16x32_bf16(
                        a[i], b[j], acc[mh*4+i][j], 0, 0, 0);
            __builtin_amdgcn_s_setprio(0);
            if (ph == 1) {
                if (more) asm volatile("s_waitcnt vmcnt(4)" ::: "memory");
                else      asm volatile("s_waitcnt vmcnt(0)" ::: "memory");
            } else if (ph == 3) {
                if (more) asm volatile("s_waitcnt vmcnt(4)" ::: "memory");
            }
            __builtin_amdgcn_s_barrier();
            __builtin_amdgcn_sched_barrier(0);
        }
    };

    for (int t = 0; t < NT - 1; ++t) tile(t, true);
    tile(NT - 1, false);

    // ---- epilogue; C/D: col = lane&15, row = (lane>>4)*4 + j ----
    float apv = 1.f; bool ap1 = true;
    if (EPI == 2) { apv = fmaxf(app[0], 0.f); ap1 = (apv == 1.0f); }
    const int cr = (lane >> 4) * 4;
    const int cc = lane & 15;
#pragma unroll
    for (int m = 0; m < 8; ++m) {
        const int grow0 = m0 + wm*128 + m*16 + cr;
#pragma unroll
        for (int n = 0; n < 4; ++n) {
            const int colb = n0 + wn*64 + n*16;   // wave-uniform -> plane uniform
            const int gcol = colb + cc;
            if (EPI == 1) {
                unsigned short* dst = (colb < H_) ? C0 : C1;
                const int pc = gcol & (H_-1);
#pragma unroll
                for (int j = 0; j < 4; ++j)
                    dst[(size_t)(grow0+j)*H_ + pc] = f2bf(acc[m][n][j]);
            } else {
                const int plane = colb >> 11;
                const int pc = gcol & (H_-1);
#pragma unroll
                for (int j = 0; j < 4; ++j) {
                    float val = acc[m][n][j] + bias[gcol];
                    const size_t off = (size_t)(grow0+j)*H_ + pc;
                    if (plane == 0) {
                        float s = 1.f/(1.f+expf(val));          // sigmoid(-f)
                        C0[off] = f2bf(ap1 ? s : powf(s, apv));
                    } else if (plane == 1) {
                        C1[off] = f2bf(sigm(val) * bflo(vsrc[off]));
                    } else {
                        C2[off] = f2bf(sigm(val));
                    }
                }
            }
        }
    }
}

// ============ 128x128 BK=64 GEMM (r4-proven; GEMM3 + fallback) ============
template<int AM, int BM, int EPI>
__global__ __launch_bounds__(256)
void mgemm(const void* __restrict__ Asrc, int lda,
           const void* __restrict__ Bsrc, int K, int N,
           const float* __restrict__ bias,
           unsigned short* __restrict__ C0, unsigned short* __restrict__ C1,
           unsigned short* __restrict__ C2, float* __restrict__ Cf,
           const unsigned short* __restrict__ vsrc, const float* __restrict__ app)
{
    __shared__ unsigned short As[128*64];
    __shared__ unsigned short Bs[128*64];
    const int tid = threadIdx.x;
    const int lane = tid & 63;
    const int wid = tid >> 6;

    const int nwg = gridDim.x * 64;
    const int orig = blockIdx.y * gridDim.x + blockIdx.x;
    const int q = nwg >> 3;
    const int wg = (orig & 7) * q + (orig >> 3);
    const int m0 = (wg & 63) * 128;
    const int n0 = (wg >> 6) * 128;

    const int ar0 = wid * 32;
    const int alr = lane >> 3;
    const int alj = lane & 7;
    const int rr = tid >> 1;
    const int kh = tid & 1;

    const int wm = wid >> 1, wn = wid & 1;
    const int fr = lane & 15, fg = lane >> 4;
    int aoff[4][2], boff[4][2];
#pragma unroll
    for (int m = 0; m < 4; ++m) {
        int row = wm*64 + m*16 + fr;
#pragma unroll
        for (int s = 0; s < 2; ++s)
            aoff[m][s] = row*128 + (((s*4 + fg) ^ (row & 7)) * 16);
    }
#pragma unroll
    for (int n = 0; n < 4; ++n) {
        int row = wn*64 + n*16 + fr;
#pragma unroll
        for (int s = 0; s < 2; ++s)
            boff[n][s] = row*128 + (((s*4 + fg) ^ (row & 7)) * 16);
    }
    const char* Asc = (const char*)As;
    const char* Bsc = (const char*)Bs;

    f4v acc[4][4];
#pragma unroll
    for (int m = 0; m < 4; ++m)
#pragma unroll
        for (int n = 0; n < 4; ++n) { f4v z4 = {0.f,0.f,0.f,0.f}; acc[m][n] = z4; }

    for (int k0 = 0; k0 < K; k0 += 64) {
        if (AM == 1) {
            const unsigned short* Ab = (const unsigned short*)Asrc;
#pragma unroll
            for (int i = 0; i < 4; ++i) {
                int row = ar0 + i*8 + alr;
                int ss = alj ^ alr;
                const char* g = (const char*)(Ab + (size_t)(m0+row)*lda + k0) + ss*16;
                gload16(g, (void*)((char*)As + (ar0 + i*8)*128));
            }
        } else {
            const float* src = (const float*)Asrc + (size_t)(m0+rr)*lda + k0 + kh*32;
            float4 v[8];
#pragma unroll
            for (int i = 0; i < 8; ++i) v[i] = ((const float4*)src)[i];
#pragma unroll
            for (int qd = 0; qd < 4; ++qd) {
                uint4 w;
                w.x = pk2(v[2*qd].x, v[2*qd].y);   w.y = pk2(v[2*qd].z, v[2*qd].w);
                w.z = pk2(v[2*qd+1].x, v[2*qd+1].y); w.w = pk2(v[2*qd+1].z, v[2*qd+1].w);
                int j = (kh*4 + qd) ^ (rr & 7);
                *(uint4*)((char*)As + rr*128 + j*16) = w;
            }
        }
        if (BM == 1) {
            const unsigned short* Bb = (const unsigned short*)Bsrc;
#pragma unroll
            for (int i = 0; i < 4; ++i) {
                int row = ar0 + i*8 + alr;
                int ss = alj ^ alr;
                const char* g = (const char*)(Bb + (size_t)(n0+row)*K + k0) + ss*16;
                gload16(g, (void*)((char*)Bs + (ar0 + i*8)*128));
            }
        } else {
            const float* src = (const float*)Bsrc + (size_t)(n0+rr)*K + k0 + kh*32;
            float4 v[8];
#pragma unroll
            for (int i = 0; i < 8; ++i) v[i] = ((const float4*)src)[i];
#pragma unroll
            for (int qd = 0; qd < 4; ++qd) {
                uint4 w;
                w.x = pk2(v[2*qd].x, v[2*qd].y);   w.y = pk2(v[2*qd].z, v[2*qd].w);
                w.z = pk2(v[2*qd+1].x, v[2*qd+1].y); w.w = pk2(v[2*qd+1].z, v[2*qd+1].w);
                int j = (kh*4 + qd) ^ (rr & 7);
                *(uint4*)((char*)Bs + rr*128 + j*16) = w;
            }
        }
        __syncthreads();
#pragma unroll
        for (int s = 0; s < 2; ++s) {
            s8v a[4], b[4];
#pragma unroll
            for (int m = 0; m < 4; ++m) a[m] = *(const s8v*)(Asc + aoff[m][s]);
#pragma unroll
            for (int n = 0; n < 4; ++n) b[n] = *(const s8v*)(Bsc + boff[n][s]);
#pragma unroll
            for (int m = 0; m < 4; ++m)
#pragma unroll
                for (int n = 0; n < 4; ++n)
                    acc[m][n] = __builtin_amdgcn_mfma_f32_16x16x32_bf16(a[m], b[n], acc[m][n], 0, 0, 0);
        }
        __syncthreads();
    }

    float apv = 1.f; bool ap1 = true;
    if (EPI == 2) { apv = fmaxf(app[0], 0.f); ap1 = (apv == 1.0f); }
    const int cr = (lane >> 4) * 4;
    const int cc = lane & 15;
#pragma unroll
    for (int m = 0; m < 4; ++m) {
        const int grow0 = m0 + wm*64 + m*16 + cr;
#pragma unroll
        for (int n = 0; n < 4; ++n) {
            const int colb = n0 + wn*64 + n*16;
            const int gcol = colb + cc;
            if (EPI == 0) {
#pragma unroll
                for (int j = 0; j < 4; ++j)
                    Cf[(size_t)(grow0+j)*N + gcol] = acc[m][n][j];
            } else if (EPI == 1) {
                unsigned short* dst = (colb < H_) ? C0 : C1;
                const int pc = gcol & (H_-1);
#pragma unroll
                for (int j = 0; j < 4; ++j)
                    dst[(size_t)(grow0+j)*H_ + pc] = f2bf(acc[m][n][j]);
            } else {
                const int plane = colb >> 11;
                const int pc = gcol & (H_-1);
#pragma unroll
                for (int j = 0; j < 4; ++j) {
                    float val = acc[m][n][j] + bias[gcol];
                    const size_t off = (size_t)(grow0+j)*H_ + pc;
                    if (plane == 0) {
                        float s = 1.f/(1.f+expf(val));
                        C0[off] = f2bf(ap1 ? s : powf(s, apv));
                    } else if (plane == 1) {
                        C1[off] = f2bf(sigm(val) * bflo(vsrc[off]));
                    } else {
                        C2[off] = f2bf(sigm(val));
                    }
                }
            }
        }
    }
}

// ============ causal depthwise conv K=4, vec8 ============
__global__ __launch_bounds__(256)
void conv8(const unsigned short* __restrict__ u, const float* __restrict__ Wc,
           const float* __restrict__ bc, unsigned short* __restrict__ v)
{
    size_t i8 = ((size_t)blockIdx.x*256 + threadIdx.x) * 8;
    int h = (int)(i8 % H_);
    size_t bt = i8 / H_;
    int t = (int)(bt % T_);
    float w[8][4], acc[8];
#pragma unroll
    for (int j = 0; j < 8; ++j) {
        float4 wr = *(const float4*)(Wc + (h+j)*4);
        w[j][0]=wr.x; w[j][1]=wr.y; w[j][2]=wr.z; w[j][3]=wr.w;
        acc[j] = bc[h+j];
    }
    const unsigned short* up = u + bt*H_ + h;
#pragma unroll
    for (int k = 0; k < 4; ++k) {
        int dt = 3 - k;
        if (t >= dt) {
            uint4 r = *(const uint4*)(up - (size_t)dt*H_);
            float e[8] = {bflo(r.x),bfhi(r.x),bflo(r.y),bfhi(r.y),
                          bflo(r.z),bfhi(r.z),bflo(r.w),bfhi(r.w)};
#pragma unroll
            for (int j = 0; j < 8; ++j) acc[j] = fmaf(e[j], w[j][k], acc[j]);
        }
    }
    uint4 o;
    o.x = pk2(acc[0],acc[1]); o.y = pk2(acc[2],acc[3]);
    o.z = pk2(acc[4],acc[5]); o.w = pk2(acc[6],acc[7]);
    *(uint4*)(v + i8) = o;
}

// ============ scan pass 1 ============
__global__ __launch_bounds__(256)
void scan_chunk8(const unsigned short* __restrict__ al, const unsigned short* __restrict__ xi,
                 float* __restrict__ cA, float* __restrict__ cB, int CT)
{
    int hh = threadIdx.x * 8;
    int c = blockIdx.y, b = blockIdx.z;
    size_t base = ((size_t)b*T_ + (size_t)c*CT)*H_ + hh;
    float A[8], Bv[8];
#pragma unroll
    for (int j=0;j<8;++j){ A[j]=1.f; Bv[j]=0.f; }
    for (int t = 0; t < CT; ++t) {
        uint4 wa = *(const uint4*)(al+base);
        uint4 wx = *(const uint4*)(xi+base);
        float a[8]={bflo(wa.x),bfhi(wa.x),bflo(wa.y),bfhi(wa.y),bflo(wa.z),bfhi(wa.z),bflo(wa.w),bfhi(wa.w)};
        float x[8]={bflo(wx.x),bfhi(wx.x),bflo(wx.y),bfhi(wx.y),bflo(wx.z),bfhi(wx.z),bflo(wx.w),bfhi(wx.w)};
#pragma unroll
        for (int j=0;j<8;++j){ A[j]*=a[j]; Bv[j]=fmaf(a[j],Bv[j],x[j]); }
        base += H_;
    }
    size_t ci = ((size_t)b*gridDim.y + c)*H_ + hh;
    *(float4*)(cA+ci)   = (float4){A[0],A[1],A[2],A[3]};
    *(float4*)(cA+ci+4) = (float4){A[4],A[5],A[6],A[7]};
    *(float4*)(cB+ci)   = (float4){Bv[0],Bv[1],Bv[2],Bv[3]};
    *(float4*)(cB+ci+4) = (float4){Bv[4],Bv[5],Bv[6],Bv[7]};
}

// ============ scan pass 2 ============
__global__ __launch_bounds__(256)
void scan_carry8(const float* __restrict__ cA, const float* __restrict__ cB,
                 float* __restrict__ cin, int NC)
{
    int gt = blockIdx.x*256 + threadIdx.x;
    int hh = (gt * 8) % H_;
    int b  = (gt * 8) / H_;
    float h[8];
#pragma unroll
    for (int j=0;j<8;++j) h[j]=0.f;
    for (int c = 0; c < NC; ++c) {
        size_t ci = ((size_t)b*NC + c)*H_ + hh;
        *(float4*)(cin+ci)   = (float4){h[0],h[1],h[2],h[3]};
        *(float4*)(cin+ci+4) = (float4){h[4],h[5],h[6],h[7]};
        float4 a0 = *(const float4*)(cA+ci), a1 = *(const float4*)(cA+ci+4);
        float4 b0 = *(const float4*)(cB+ci), b1 = *(const float4*)(cB+ci+4);
        float a[8]={a0.x,a0.y,a0.z,a0.w,a1.x,a1.y,a1.z,a1.w};
        float x[8]={b0.x,b0.y,b0.z,b0.w,b1.x,b1.y,b1.z,b1.w};
#pragma unroll
        for (int j=0;j<8;++j) h[j] = fmaf(a[j], h[j], x[j]);
    }
}

// ============ scan pass 3 ============
__global__ __launch_bounds__(256)
void scan_apply8(const unsigned short* __restrict__ al, const unsigned short* __restrict__ xi,
                 const unsigned short* __restrict__ so, const unsigned short* __restrict__ ga,
                 const float* __restrict__ cin, unsigned short* __restrict__ z, int CT)
{
    int hh = threadIdx.x * 8;
    int c = blockIdx.y, b = blockIdx.z;
    size_t base = ((size_t)b*T_ + (size_t)c*CT)*H_ + hh;
    size_t ci = ((size_t)b*gridDim.y + c)*H_ + hh;
    float h[8];
    {
        float4 h0 = *(const float4*)(cin+ci), h1 = *(const float4*)(cin+ci+4);
        h[0]=h0.x; h[1]=h0.y; h[2]=h0.z; h[3]=h0.w;
        h[4]=h1.x; h[5]=h1.y; h[6]=h1.z; h[7]=h1.w;
    }
    for (int t = 0; t < CT; ++t) {
        uint4 wa = *(const uint4*)(al+base);
        uint4 wx = *(const uint4*)(xi+base);
        uint4 ws_ = *(const uint4*)(so+base);
        uint4 wg = *(const uint4*)(ga+base);
        float a[8]={bflo(wa.x),bfhi(wa.x),bflo(wa.y),bfhi(wa.y),bflo(wa.z),bfhi(wa.z),bflo(wa.w),bfhi(wa.w)};
        float x[8]={bflo(wx.x),bfhi(wx.x),bflo(wx.y),bfhi(wx.y),bflo(wx.z),bfhi(wx.z),bflo(wx.w),bfhi(wx.w)};
        float s[8]={bflo(ws_.x),bfhi(ws_.x),bflo(ws_.y),bfhi(ws_.y),bflo(ws_.z),bfhi(ws_.z),bflo(ws_.w),bfhi(ws_.w)};
        float g[8]={bflo(wg.x),bfhi(wg.x),bflo(wg.y),bfhi(wg.y),bflo(wg.z),bfhi(wg.z),bflo(wg.w),bfhi(wg.w)};
        float zo[8];
#pragma unroll
        for (int j=0;j<8;++j) {
            h[j] = fmaf(a[j], h[j], x[j]);
            float ge = 0.5f*g[j]*(1.f+erff(g[j]*0.70710678118654752f));
            zo[j] = ge * s[j] * h[j];
        }
        uint4 o;
        o.x = pk2(zo[0],zo[1]); o.y = pk2(zo[2],zo[3]);
        o.z = pk2(zo[4],zo[5]); o.w = pk2(zo[6],zo[7]);
        *(uint4*)(z + base) = o;
        base += H_;
    }
}

__global__ void zero_out(float* __restrict__ out, size_t n)
{
    for (size_t i = (size_t)blockIdx.x*256 + threadIdx.x; i < n; i += (size_t)gridDim.x*256)
        out[i] = 0.f;
}

extern "C" void kernel_launch(void* const* d_in, const int* in_sizes, int n_in,
                              void* d_out, int out_size, void* d_ws, size_t ws_size,
                              hipStream_t stream)
{
    const float* x       = (const float*)d_in[0];
    const float* W_in    = (const float*)d_in[1];
    const float* W_conv  = (const float*)d_in[2];
    const float* b_conv  = (const float*)d_in[3];
    const float* W_gates = (const float*)d_in[4];
    const float* b_gates = (const float*)d_in[5];
    const float* W_out   = (const float*)d_in[6];
    const float* alpha_p = (const float*)d_in[7];
    float* out = (float*)d_out;

    const size_t plane = (size_t)B_ * T_ * H_;   // 16.78M elems
    unsigned short* gate = (unsigned short*)d_ws;
    unsigned short* u    = gate + plane;   // -> alpha after GEMM2
    unsigned short* v    = u + plane;      // -> z after scan
    unsigned short* xin  = v + plane;
    unsigned short* so   = xin + plane;
    char* R = (char*)(so + plane);         // time-shared region

    const size_t x_elems  = (size_t)B_*T_*D_;
    const size_t wg_elems = (size_t)3*H_*H_;
    const size_t wi_elems = (size_t)2*H_*D_;
    const size_t wo_elems = (size_t)D_*H_;
    const int NCF = 64;
    const size_t carry_b = 3*(size_t)B_*NCF*H_*4;
    const size_t Rneed = x_elems*2 > carry_b + wo_elems*2 ? x_elems*2 : carry_b + wo_elems*2;
    const size_t need_fast = 5*plane*2 + Rneed;

    if (ws_size >= need_fast && (size_t)out_size*4 >= (wg_elems + wi_elems)*2) {
        // ---------- fast path: 4-phase counted-vmcnt 256^2 GEMM1/2 ----------
        unsigned short* wgb  = (unsigned short*)d_out;      // dead before GEMM3 writes out
        unsigned short* winb = wgb + wg_elems;
        unsigned short* xb   = (unsigned short*)R;          // live through GEMM1
        float* cAp  = (float*)R;                            // written after GEMM1
        float* cBp  = cAp + (size_t)B_*NCF*H_;
        float* cinp = cBp + (size_t)B_*NCF*H_;
        unsigned short* woutb = (unsigned short*)(cinp + (size_t)B_*NCF*H_);
        const int CT = T_ / NCF;

        cvt8<<<(unsigned)(x_elems/2048),  256, 0, stream>>>(x, xb);
        cvt8<<<(unsigned)(wi_elems/2048), 256, 0, stream>>>(W_in, winb);
        cvt8<<<(unsigned)(wg_elems/2048), 256, 0, stream>>>(W_gates, wgb);
        // GEMM1: gate|u = x @ W_in^T
        pgemm8<1><<<dim3(512), 512, 0, stream>>>(
            xb, D_, winb, D_, 2*H_, nullptr, gate, u, nullptr, nullptr, nullptr);
        conv8<<<(unsigned)(plane/8/256), 256, 0, stream>>>(u, W_conv, b_conv, v);
        cvt8<<<(unsigned)(wo_elems/2048), 256, 0, stream>>>(W_out, woutb);  // xb dead
        // GEMM2: alpha|xin|so = f(v @ W_gates^T + b)
        pgemm8<2><<<dim3(768), 512, 0, stream>>>(
            v, H_, wgb, H_, 3*H_, b_gates, u, xin, so, v, alpha_p);
        scan_chunk8<<<dim3(1,NCF,B_), 256, 0, stream>>>(u, xin, cAp, cBp, CT);
        scan_carry8<<<(B_*H_/8)/256, 256, 0, stream>>>(cAp, cBp, cinp, NCF);
        scan_apply8<<<dim3(1,NCF,B_), 256, 0, stream>>>(u, xin, so, gate, cinp, v, CT);
        // GEMM3: out = z @ W_out^T  (r4-proven 128^2 kernel; small N)
        mgemm<1,1,0><<<dim3(8,64), 256, 0, stream>>>(
            v, H_, woutb, H_, D_, nullptr, nullptr, nullptr, nullptr, out, nullptr, nullptr);
        return;
    }

    // ---------- fallback: round-3 proven path ----------
    float* cAp = (float*)R;
    int NC = 64;
    if (ws_size < 5*plane*2 + 3*(size_t)B_*64*H_*4) {
        NC = 16;
        if (ws_size < 5*plane*2 + 3*(size_t)B_*16*H_*4) {
            zero_out<<<2048, 256, 0, stream>>>(out, (size_t)out_size);
            return;
        }
    }
    const int CT = T_ / NC;
    float* cBp  = cAp + (size_t)B_*NC*H_;
    float* cinp = cBp + (size_t)B_*NC*H_;

    mgemm<0,0,1><<<dim3(32,64), 256, 0, stream>>>(
        x, D_, W_in, D_, 2*H_, nullptr, gate, u, nullptr, nullptr, nullptr, nullptr);
    conv8<<<(unsigned)(plane/8/256), 256, 0, stream>>>(u, W_conv, b_conv, v);
    mgemm<1,0,2><<<dim3(48,64), 256, 0, stream>>>(
        v, H_, W_gates, H_, 3*H_, b_gates, u, xin, so, nullptr, v, alpha_p);
    scan_chunk8<<<dim3(1,NC,B_), 256, 0, stream>>>(u, xin, cAp, cBp, CT);
    scan_carry8<<<(B_*H_/8)/256, 256, 0, stream>>>(cAp, cBp, cinp, NC);
    scan_apply8<<<dim3(1,NC,B_), 256, 0, stream>>>(u, xin, so, gate, cinp, v, CT);
    mgemm<1,0,0><<<dim3(8,64), 256, 0, stream>>>(
        v, H_, W_out, H_, D_, nullptr, nullptr, nullptr, nullptr, out, nullptr, nullptr);
}

// Round 10
// 643.670 us; speedup vs baseline: 6.3055x; 1.0058x over previous
//
#include <hip/hip_runtime.h>
#include <hip/hip_bf16.h>
#include <cstdint>
#include <cstddef>

#define B_ 4
#define T_ 2048
#define D_ 1024
#define H_ 2048

typedef __attribute__((ext_vector_type(8))) short s8v;   // 8 bf16 (4 VGPR)
typedef __attribute__((ext_vector_type(4))) float f4v;   // 4 f32 acc

__device__ __forceinline__ float bflo(unsigned int u){ union{unsigned int i;float f;}c; c.i=u<<16; return c.f; }
__device__ __forceinline__ float bfhi(unsigned int u){ union{unsigned int i;float f;}c; c.i=u&0xffff0000u; return c.f; }
__device__ __forceinline__ unsigned short f2bf(float f){
    __hip_bfloat16 h = __float2bfloat16(f);
    union { __hip_bfloat16 h; unsigned short u; } c; c.h = h; return c.u;
}
__device__ __forceinline__ unsigned int pk2(float lo, float hi){
    return (unsigned int)f2bf(lo) | ((unsigned int)f2bf(hi) << 16);
}
__device__ __forceinline__ float sigm(float x){ return 1.f/(1.f+expf(-x)); }
__device__ __forceinline__ void up8(uint4 w, float* r){
    r[0]=bflo(w.x); r[1]=bfhi(w.x); r[2]=bflo(w.y); r[3]=bfhi(w.y);
    r[4]=bflo(w.z); r[5]=bfhi(w.z); r[6]=bflo(w.w); r[7]=bfhi(w.w);
}

__device__ __forceinline__ void gload16(const void* g, void* l){
    __builtin_amdgcn_global_load_lds(
        (const __attribute__((address_space(1))) unsigned int*)g,
        (__attribute__((address_space(3))) unsigned int*)l, 16, 0, 0);
}

// ============ fp32 -> bf16 conversion, vec8 ============
__global__ __launch_bounds__(256)
void cvt8(const float* __restrict__ s, unsigned short* __restrict__ d)
{
    size_t i = ((size_t)blockIdx.x*256 + threadIdx.x)*8;
    float4 a = *(const float4*)(s+i), b = *(const float4*)(s+i+4);
    uint4 o; o.x=pk2(a.x,a.y); o.y=pk2(a.z,a.w); o.z=pk2(b.x,b.y); o.w=pk2(b.z,b.w);
    *(uint4*)(d+i)=o;
}

// ======================================================================
// 128x128 MFMA GEMM, BK=64, 4 waves, 16KB-LDS-x2 (r4-proven structure,
// best measured GEMM on this problem: GEMM2 = 330us). Per K-step:
// 8 gload16 + 8 ds_read_b128 + 16 MFMA + 2 barriers.
// AM/BM: 1 = bf16 src via global_load_lds w=16 (slot-XOR swizzle, rule 21:
//   linear LDS dest + inverse-swizzled GLOBAL source + swizzled ds_read,
//   HW-verified 0 bank conflicts); 0 = fp32 src reg-staged + cvt.
// EPI 0: f32 store to Cf. EPI 1: N=4096 split gate|u -> C0,C1 (bf16).
// EPI 2: N=6144 RAW 3-plane split f|i|o -> C0,C1,C2 (bf16, NO transforms:
//   gate math moved to the memory-bound scan kernels where VALU is free --
//   r4's VALUBusy=50% vs r9's 22% fingerprinted the epilogue transcendentals
//   as a GEMM-side serial cost).
// ======================================================================
template<int AM, int BM, int EPI>
__global__ __launch_bounds__(256)
void mgemm(const void* __restrict__ Asrc, int lda,
           const void* __restrict__ Bsrc, int K, int N,
           unsigned short* __restrict__ C0, unsigned short* __restrict__ C1,
           unsigned short* __restrict__ C2, float* __restrict__ Cf)
{
    __shared__ unsigned short As[128*64];
    __shared__ unsigned short Bs[128*64];
    const int tid = threadIdx.x;
    const int lane = tid & 63;
    const int wid = tid >> 6;

    const int nwg = gridDim.x * 64;
    const int orig = blockIdx.y * gridDim.x + blockIdx.x;
    const int q = nwg >> 3;
    const int wg = (orig & 7) * q + (orig >> 3);
    const int m0 = (wg & 63) * 128;
    const int n0 = (wg >> 6) * 128;

    const int ar0 = wid * 32;
    const int alr = lane >> 3;
    const int alj = lane & 7;
    const int rr = tid >> 1;
    const int kh = tid & 1;

    const int wm = wid >> 1, wn = wid & 1;
    const int fr = lane & 15, fg = lane >> 4;
    int aoff[4][2], boff[4][2];
#pragma unroll
    for (int m = 0; m < 4; ++m) {
        int row = wm*64 + m*16 + fr;
#pragma unroll
        for (int s = 0; s < 2; ++s)
            aoff[m][s] = row*128 + (((s*4 + fg) ^ (row & 7)) * 16);
    }
#pragma unroll
    for (int n = 0; n < 4; ++n) {
        int row = wn*64 + n*16 + fr;
#pragma unroll
        for (int s = 0; s < 2; ++s)
            boff[n][s] = row*128 + (((s*4 + fg) ^ (row & 7)) * 16);
    }
    const char* Asc = (const char*)As;
    const char* Bsc = (const char*)Bs;

    f4v acc[4][4];
#pragma unroll
    for (int m = 0; m < 4; ++m)
#pragma unroll
        for (int n = 0; n < 4; ++n) { f4v z4 = {0.f,0.f,0.f,0.f}; acc[m][n] = z4; }

    for (int k0 = 0; k0 < K; k0 += 64) {
        if (AM == 1) {
            const unsigned short* Ab = (const unsigned short*)Asrc;
#pragma unroll
            for (int i = 0; i < 4; ++i) {
                int row = ar0 + i*8 + alr;
                int ss = alj ^ alr;
                const char* g = (const char*)(Ab + (size_t)(m0+row)*lda + k0) + ss*16;
                gload16(g, (void*)((char*)As + (ar0 + i*8)*128));
            }
        } else {
            const float* src = (const float*)Asrc + (size_t)(m0+rr)*lda + k0 + kh*32;
            float4 v[8];
#pragma unroll
            for (int i = 0; i < 8; ++i) v[i] = ((const float4*)src)[i];
#pragma unroll
            for (int qd = 0; qd < 4; ++qd) {
                uint4 w;
                w.x = pk2(v[2*qd].x, v[2*qd].y);   w.y = pk2(v[2*qd].z, v[2*qd].w);
                w.z = pk2(v[2*qd+1].x, v[2*qd+1].y); w.w = pk2(v[2*qd+1].z, v[2*qd+1].w);
                int j = (kh*4 + qd) ^ (rr & 7);
                *(uint4*)((char*)As + rr*128 + j*16) = w;
            }
        }
        if (BM == 1) {
            const unsigned short* Bb = (const unsigned short*)Bsrc;
#pragma unroll
            for (int i = 0; i < 4; ++i) {
                int row = ar0 + i*8 + alr;
                int ss = alj ^ alr;
                const char* g = (const char*)(Bb + (size_t)(n0+row)*K + k0) + ss*16;
                gload16(g, (void*)((char*)Bs + (ar0 + i*8)*128));
            }
        } else {
            const float* src = (const float*)Bsrc + (size_t)(n0+rr)*K + k0 + kh*32;
            float4 v[8];
#pragma unroll
            for (int i = 0; i < 8; ++i) v[i] = ((const float4*)src)[i];
#pragma unroll
            for (int qd = 0; qd < 4; ++qd) {
                uint4 w;
                w.x = pk2(v[2*qd].x, v[2*qd].y);   w.y = pk2(v[2*qd].z, v[2*qd].w);
                w.z = pk2(v[2*qd+1].x, v[2*qd+1].y); w.w = pk2(v[2*qd+1].z, v[2*qd+1].w);
                int j = (kh*4 + qd) ^ (rr & 7);
                *(uint4*)((char*)Bs + rr*128 + j*16) = w;
            }
        }
        __syncthreads();
#pragma unroll
        for (int s = 0; s < 2; ++s) {
            s8v a[4], b[4];
#pragma unroll
            for (int m = 0; m < 4; ++m) a[m] = *(const s8v*)(Asc + aoff[m][s]);
#pragma unroll
            for (int n = 0; n < 4; ++n) b[n] = *(const s8v*)(Bsc + boff[n][s]);
#pragma unroll
            for (int m = 0; m < 4; ++m)
#pragma unroll
                for (int n = 0; n < 4; ++n)
                    acc[m][n] = __builtin_amdgcn_mfma_f32_16x16x32_bf16(a[m], b[n], acc[m][n], 0, 0, 0);
        }
        __syncthreads();
    }

    // ---- epilogue; C/D: col = lane&15, row = (lane>>4)*4 + j  [m89] ----
    const int cr = (lane >> 4) * 4;
    const int cc = lane & 15;
#pragma unroll
    for (int m = 0; m < 4; ++m) {
        const int grow0 = m0 + wm*64 + m*16 + cr;
#pragma unroll
        for (int n = 0; n < 4; ++n) {
            const int colb = n0 + wn*64 + n*16;   // wave-uniform -> plane uniform
            const int gcol = colb + cc;
            if (EPI == 0) {
#pragma unroll
                for (int j = 0; j < 4; ++j)
                    Cf[(size_t)(grow0+j)*N + gcol] = acc[m][n][j];
            } else if (EPI == 1) {
                unsigned short* dst = (colb < H_) ? C0 : C1;
                const int pc = gcol & (H_-1);
#pragma unroll
                for (int j = 0; j < 4; ++j)
                    dst[(size_t)(grow0+j)*H_ + pc] = f2bf(acc[m][n][j]);
            } else {   // EPI == 2: raw f|i|o planes
                const int plane = colb >> 11;
                unsigned short* dst = (plane == 0) ? C0 : ((plane == 1) ? C1 : C2);
                const int pc = gcol & (H_-1);
#pragma unroll
                for (int j = 0; j < 4; ++j)
                    dst[(size_t)(grow0+j)*H_ + pc] = f2bf(acc[m][n][j]);
            }
        }
    }
}

// ============ causal depthwise conv K=4, vec8 ============
__global__ __launch_bounds__(256)
void conv8(const unsigned short* __restrict__ u, const float* __restrict__ Wc,
           const float* __restrict__ bc, unsigned short* __restrict__ v)
{
    size_t i8 = ((size_t)blockIdx.x*256 + threadIdx.x) * 8;
    int h = (int)(i8 % H_);
    size_t bt = i8 / H_;
    int t = (int)(bt % T_);
    float w[8][4], acc[8];
#pragma unroll
    for (int j = 0; j < 8; ++j) {
        float4 wr = *(const float4*)(Wc + (h+j)*4);
        w[j][0]=wr.x; w[j][1]=wr.y; w[j][2]=wr.z; w[j][3]=wr.w;
        acc[j] = bc[h+j];
    }
    const unsigned short* up = u + bt*H_ + h;
#pragma unroll
    for (int k = 0; k < 4; ++k) {
        int dt = 3 - k;
        if (t >= dt) {
            uint4 r = *(const uint4*)(up - (size_t)dt*H_);
            float e[8]; up8(r, e);
#pragma unroll
            for (int j = 0; j < 8; ++j) acc[j] = fmaf(e[j], w[j][k], acc[j]);
        }
    }
    uint4 o;
    o.x = pk2(acc[0],acc[1]); o.y = pk2(acc[2],acc[3]);
    o.z = pk2(acc[4],acc[5]); o.w = pk2(acc[6],acc[7]);
    *(uint4*)(v + i8) = o;
}

// ============ scan pass 1: per-chunk fold, transforms fused (VALU free) ====
__global__ __launch_bounds__(256)
void scan_chunk8(const unsigned short* __restrict__ fp, const unsigned short* __restrict__ ip,
                 const unsigned short* __restrict__ vp,
                 const float* __restrict__ bg, const float* __restrict__ app,
                 float* __restrict__ cA, float* __restrict__ cB, int CT)
{
    int hh = threadIdx.x * 8;
    int c = blockIdx.y, b = blockIdx.z;
    const float ap = fmaxf(app[0], 0.f);
    const bool ap1 = (ap == 1.0f);
    float bf[8], bi[8];
#pragma unroll
    for (int j = 0; j < 8; ++j) { bf[j] = bg[hh+j]; bi[j] = bg[H_+hh+j]; }
    size_t base = ((size_t)b*T_ + (size_t)c*CT)*H_ + hh;
    float A[8], Bv[8];
#pragma unroll
    for (int j=0;j<8;++j){ A[j]=1.f; Bv[j]=0.f; }
    for (int t = 0; t < CT; ++t) {
        float f[8], i8a[8], v[8];
        up8(*(const uint4*)(fp+base), f);
        up8(*(const uint4*)(ip+base), i8a);
        up8(*(const uint4*)(vp+base), v);
#pragma unroll
        for (int j=0;j<8;++j){
            float s = 1.f/(1.f+expf(f[j]+bf[j]));          // sigmoid(-(f+bf))
            float a = ap1 ? s : powf(s, ap);
            float xin = v[j] / (1.f+expf(-(i8a[j]+bi[j]))); // sigm(i+bi)*v
            A[j]*=a; Bv[j]=fmaf(a,Bv[j],xin);
        }
        base += H_;
    }
    size_t ci = ((size_t)b*gridDim.y + c)*H_ + hh;
    *(float4*)(cA+ci)   = (float4){A[0],A[1],A[2],A[3]};
    *(float4*)(cA+ci+4) = (float4){A[4],A[5],A[6],A[7]};
    *(float4*)(cB+ci)   = (float4){Bv[0],Bv[1],Bv[2],Bv[3]};
    *(float4*)(cB+ci+4) = (float4){Bv[4],Bv[5],Bv[6],Bv[7]};
}

// ============ scan pass 2: sequential carry across chunks ============
__global__ __launch_bounds__(256)
void scan_carry8(const float* __restrict__ cA, const float* __restrict__ cB,
                 float* __restrict__ cin, int NC)
{
    int gt = blockIdx.x*256 + threadIdx.x;
    int hh = (gt * 8) % H_;
    int b  = (gt * 8) / H_;
    float h[8];
#pragma unroll
    for (int j=0;j<8;++j) h[j]=0.f;
    for (int c = 0; c < NC; ++c) {
        size_t ci = ((size_t)b*NC + c)*H_ + hh;
        *(float4*)(cin+ci)   = (float4){h[0],h[1],h[2],h[3]};
        *(float4*)(cin+ci+4) = (float4){h[4],h[5],h[6],h[7]};
        float4 a0 = *(const float4*)(cA+ci), a1 = *(const float4*)(cA+ci+4);
        float4 b0 = *(const float4*)(cB+ci), b1 = *(const float4*)(cB+ci+4);
        float a[8]={a0.x,a0.y,a0.z,a0.w,a1.x,a1.y,a1.z,a1.w};
        float x[8]={b0.x,b0.y,b0.z,b0.w,b1.x,b1.y,b1.z,b1.w};
#pragma unroll
        for (int j=0;j<8;++j) h[j] = fmaf(a[j], h[j], x[j]);
    }
}

// ============ scan pass 3: re-scan + full gate math; z written into v ====
__global__ __launch_bounds__(256)
void scan_apply8(const unsigned short* __restrict__ fp, const unsigned short* __restrict__ ip,
                 const unsigned short* __restrict__ op, const unsigned short* __restrict__ ga,
                 unsigned short* __restrict__ vz,   // v plane read, z written in place
                 const float* __restrict__ bg, const float* __restrict__ app,
                 const float* __restrict__ cin, int CT)
{
    int hh = threadIdx.x * 8;
    int c = blockIdx.y, b = blockIdx.z;
    const float ap = fmaxf(app[0], 0.f);
    const bool ap1 = (ap == 1.0f);
    float bf[8], bi[8], bo[8];
#pragma unroll
    for (int j = 0; j < 8; ++j) {
        bf[j] = bg[hh+j]; bi[j] = bg[H_+hh+j]; bo[j] = bg[2*H_+hh+j];
    }
    size_t base = ((size_t)b*T_ + (size_t)c*CT)*H_ + hh;
    size_t ci = ((size_t)b*gridDim.y + c)*H_ + hh;
    float h[8];
    {
        float4 h0 = *(const float4*)(cin+ci), h1 = *(const float4*)(cin+ci+4);
        h[0]=h0.x; h[1]=h0.y; h[2]=h0.z; h[3]=h0.w;
        h[4]=h1.x; h[5]=h1.y; h[6]=h1.z; h[7]=h1.w;
    }
    for (int t = 0; t < CT; ++t) {
        float f[8], i8a[8], o8[8], g[8], v[8], zo[8];
        up8(*(const uint4*)(fp+base), f);
        up8(*(const uint4*)(ip+base), i8a);
        up8(*(const uint4*)(op+base), o8);
        up8(*(const uint4*)(ga+base), g);
        up8(*(const uint4*)(vz+base), v);
#pragma unroll
        for (int j=0;j<8;++j) {
            float s = 1.f/(1.f+expf(f[j]+bf[j]));
            float a = ap1 ? s : powf(s, ap);
            float xin = v[j] / (1.f+expf(-(i8a[j]+bi[j])));
            h[j] = fmaf(a, h[j], xin);
            float so = 1.f/(1.f+expf(-(o8[j]+bo[j])));
            float ge = 0.5f*g[j]*(1.f+erff(g[j]*0.70710678118654752f));
            zo[j] = ge * so * h[j];
        }
        uint4 o;
        o.x = pk2(zo[0],zo[1]); o.y = pk2(zo[2],zo[3]);
        o.z = pk2(zo[4],zo[5]); o.w = pk2(zo[6],zo[7]);
        *(uint4*)(vz + base) = o;
        base += H_;
    }
}

__global__ void zero_out(float* __restrict__ out, size_t n)
{
    for (size_t i = (size_t)blockIdx.x*256 + threadIdx.x; i < n; i += (size_t)gridDim.x*256)
        out[i] = 0.f;
}

extern "C" void kernel_launch(void* const* d_in, const int* in_sizes, int n_in,
                              void* d_out, int out_size, void* d_ws, size_t ws_size,
                              hipStream_t stream)
{
    const float* x       = (const float*)d_in[0];
    const float* W_in    = (const float*)d_in[1];
    const float* W_conv  = (const float*)d_in[2];
    const float* b_conv  = (const float*)d_in[3];
    const float* W_gates = (const float*)d_in[4];
    const float* b_gates = (const float*)d_in[5];
    const float* W_out   = (const float*)d_in[6];
    const float* alpha_p = (const float*)d_in[7];
    float* out = (float*)d_out;

    const size_t plane = (size_t)B_ * T_ * H_;   // 16.78M elems
    // planes: gate | f(=u slot) | v(->z) | i | o
    unsigned short* gate = (unsigned short*)d_ws;
    unsigned short* fpl  = gate + plane;   // u during GEMM1/conv, then raw f
    unsigned short* v    = fpl + plane;    // v, then z in place
    unsigned short* ipl  = v + plane;
    unsigned short* opl  = ipl + plane;
    char* R = (char*)(opl + plane);        // time-shared region

    const size_t x_elems  = (size_t)B_*T_*D_;
    const size_t wg_elems = (size_t)3*H_*H_;
    const size_t wi_elems = (size_t)2*H_*D_;
    const size_t wo_elems = (size_t)D_*H_;
    const int NCF = 64;
    const size_t carry_b = 3*(size_t)B_*NCF*H_*4;
    const size_t Rneed = x_elems*2 > carry_b + wo_elems*2 ? x_elems*2 : carry_b + wo_elems*2;
    const size_t need_fast = 5*plane*2 + Rneed;

    if (ws_size >= need_fast && (size_t)out_size*4 >= (wg_elems + wi_elems)*2) {
        // ---------- fast path ----------
        unsigned short* wgb  = (unsigned short*)d_out;      // dead before GEMM3 writes out
        unsigned short* winb = wgb + wg_elems;
        unsigned short* xb   = (unsigned short*)R;          // live through GEMM1
        float* cAp  = (float*)R;                            // written after GEMM1
        float* cBp  = cAp + (size_t)B_*NCF*H_;
        float* cinp = cBp + (size_t)B_*NCF*H_;
        unsigned short* woutb = (unsigned short*)(cinp + (size_t)B_*NCF*H_);
        const int CT = T_ / NCF;

        cvt8<<<(unsigned)(x_elems/2048),  256, 0, stream>>>(x, xb);
        cvt8<<<(unsigned)(wi_elems/2048), 256, 0, stream>>>(W_in, winb);
        cvt8<<<(unsigned)(wg_elems/2048), 256, 0, stream>>>(W_gates, wgb);
        // GEMM1: gate|u = x @ W_in^T
        mgemm<1,1,1><<<dim3(32,64), 256, 0, stream>>>(
            xb, D_, winb, D_, 2*H_, gate, fpl, nullptr, nullptr);
        conv8<<<(unsigned)(plane/8/256), 256, 0, stream>>>(fpl, W_conv, b_conv, v);
        cvt8<<<(unsigned)(wo_elems/2048), 256, 0, stream>>>(W_out, woutb);  // xb dead
        // GEMM2: raw f|i|o = v @ W_gates^T   (f overwrites u slot)
        mgemm<1,1,2><<<dim3(48,64), 256, 0, stream>>>(
            v, H_, wgb, H_, 3*H_, fpl, ipl, opl, nullptr);
        scan_chunk8<<<dim3(1,NCF,B_), 256, 0, stream>>>(fpl, ipl, v, b_gates, alpha_p, cAp, cBp, CT);
        scan_carry8<<<(B_*H_/8)/256, 256, 0, stream>>>(cAp, cBp, cinp, NCF);
        scan_apply8<<<dim3(1,NCF,B_), 256, 0, stream>>>(fpl, ipl, opl, gate, v, b_gates, alpha_p, cinp, CT);
        // GEMM3: out = z @ W_out^T
        mgemm<1,1,0><<<dim3(8,64), 256, 0, stream>>>(
            v, H_, woutb, H_, D_, nullptr, nullptr, nullptr, out);
        return;
    }

    // ---------- fallback (same scheme, fp32 sources reg-staged) ----------
    float* cAp = (float*)R;
    int NC = 64;
    if (ws_size < 5*plane*2 + 3*(size_t)B_*64*H_*4) {
        NC = 16;
        if (ws_size < 5*plane*2 + 3*(size_t)B_*16*H_*4) {
            zero_out<<<2048, 256, 0, stream>>>(out, (size_t)out_size);
            return;
        }
    }
    const int CT = T_ / NC;
    float* cBp  = cAp + (size_t)B_*NC*H_;
    float* cinp = cBp + (size_t)B_*NC*H_;

    mgemm<0,0,1><<<dim3(32,64), 256, 0, stream>>>(
        x, D_, W_in, D_, 2*H_, gate, fpl, nullptr, nullptr);
    conv8<<<(unsigned)(plane/8/256), 256, 0, stream>>>(fpl, W_conv, b_conv, v);
    mgemm<1,0,2><<<dim3(48,64), 256, 0, stream>>>(
        v, H_, W_gates, H_, 3*H_, fpl, ipl, opl, nullptr);
    scan_chunk8<<<dim3(1,NC,B_), 256, 0, stream>>>(fpl, ipl, v, b_gates, alpha_p, cAp, cBp, CT);
    scan_carry8<<<(B_*H_/8)/256, 256, 0, stream>>>(cAp, cBp, cinp, NC);
    scan_apply8<<<dim3(1,NC,B_), 256, 0, stream>>>(fpl, ipl, opl, gate, v, b_gates, alpha_p, cinp, CT);
    mgemm<1,0,0><<<dim3(8,64), 256, 0, stream>>>(
        v, H_, W_out, H_, D_, nullptr, nullptr, nullptr, out);
}

// Round 11
// 577.479 us; speedup vs baseline: 7.0282x; 1.1146x over previous
//
#include <hip/hip_runtime.h>
#include <hip/hip_bf16.h>
#include <cstdint>
#include <cstddef>

#define B_ 4
#define T_ 2048
#define D_ 1024
#define H_ 2048

typedef __attribute__((ext_vector_type(8))) short s8v;   // 8 bf16 (4 VGPR)
typedef __attribute__((ext_vector_type(4))) float f4v;   // 4 f32 acc

__device__ __forceinline__ float bflo(unsigned int u){ union{unsigned int i;float f;}c; c.i=u<<16; return c.f; }
__device__ __forceinline__ float bfhi(unsigned int u){ union{unsigned int i;float f;}c; c.i=u&0xffff0000u; return c.f; }
__device__ __forceinline__ unsigned short f2bf(float f){
    __hip_bfloat16 h = __float2bfloat16(f);
    union { __hip_bfloat16 h; unsigned short u; } c; c.h = h; return c.u;
}
__device__ __forceinline__ unsigned int pk2(float lo, float hi){
    return (unsigned int)f2bf(lo) | ((unsigned int)f2bf(hi) << 16);
}
__device__ __forceinline__ float sigm(float x){ return 1.f/(1.f+expf(-x)); }
__device__ __forceinline__ void up8(uint4 w, float* r){
    r[0]=bflo(w.x); r[1]=bfhi(w.x); r[2]=bflo(w.y); r[3]=bfhi(w.y);
    r[4]=bflo(w.z); r[5]=bfhi(w.z); r[6]=bflo(w.w); r[7]=bfhi(w.w);
}

__device__ __forceinline__ void gload16(const void* g, void* l){
    __builtin_amdgcn_global_load_lds(
        (const __attribute__((address_space(1))) unsigned int*)g,
        (__attribute__((address_space(3))) unsigned int*)l, 16, 0, 0);
}

// ============ fp32 -> bf16 conversion, vec8 ============
__global__ __launch_bounds__(256)
void cvt8(const float* __restrict__ s, unsigned short* __restrict__ d)
{
    size_t i = ((size_t)blockIdx.x*256 + threadIdx.x)*8;
    float4 a = *(const float4*)(s+i), b = *(const float4*)(s+i+4);
    uint4 o; o.x=pk2(a.x,a.y); o.y=pk2(a.z,a.w); o.z=pk2(b.x,b.y); o.w=pk2(b.z,b.w);
    *(uint4*)(d+i)=o;
}

// ======================================================================
// 128x128 MFMA GEMM, BK=64, 4 waves, 16KB-LDS-x2 (r4/r10-proven; GEMM2
// = 248us, MfmaUtil 38% = m97 ceiling). Per K-step: 8 gload16 +
// 8 ds_read_b128 + 16 MFMA + 2 barriers.
// NEW (r11): L2-blocked XCD mapping. r10's m-fastest chunk swept 64
// A-panels (32MB) through the 4MB per-XCD L2 each n-column -> FETCH=772MB
// (13x operand size), L2-fill-bound. Now each XCD owns 8 m-panels,
// iterated in 2 groups of 4 (2MB A-set resident beside 0.5MB B-panel),
// n-outer / m-fastest-inner: predicted FETCH ~420MB.
// AM/BM: 1 = bf16 src via global_load_lds w=16 (slot-XOR swizzle, rule 21);
// 0 = fp32 src reg-staged + cvt.
// EPI 0: f32 -> Cf. EPI 1: split gate|u. EPI 2: raw f|i|o (transforms
// live in the memory-bound scan kernels -- r10-verified win).
// ======================================================================
template<int AM, int BM, int EPI>
__global__ __launch_bounds__(256)
void mgemm(const void* __restrict__ Asrc, int lda,
           const void* __restrict__ Bsrc, int K, int N,
           unsigned short* __restrict__ C0, unsigned short* __restrict__ C1,
           unsigned short* __restrict__ C2, float* __restrict__ Cf)
{
    __shared__ unsigned short As[128*64];
    __shared__ unsigned short Bs[128*64];
    const int tid = threadIdx.x;
    const int lane = tid & 63;
    const int wid = tid >> 6;

    // L2-blocked XCD mapping: xcd owns m-panels [xcd*8, xcd*8+8), split in
    // 2 groups of 4; within a group n is outer, m_local (0..3) fastest.
    const int nxb = gridDim.x;                 // N/128
    const int orig = blockIdx.y * nxb + blockIdx.x;
    const int xcd = orig & 7;
    const int i = orig >> 3;                   // [0, 8*nxb)
    const int gsz = nxb << 2;                  // 4*nxb per group
    const int g = i / gsz;                     // 0 or 1
    const int r = i - g * gsz;
    const int n0 = (r >> 2) * 128;
    const int m0 = (xcd * 8 + g * 4 + (r & 3)) * 128;

    const int ar0 = wid * 32;
    const int alr = lane >> 3;
    const int alj = lane & 7;
    const int rr = tid >> 1;
    const int kh = tid & 1;

    const int wm = wid >> 1, wn = wid & 1;
    const int fr = lane & 15, fg = lane >> 4;
    int aoff[4][2], boff[4][2];
#pragma unroll
    for (int m = 0; m < 4; ++m) {
        int row = wm*64 + m*16 + fr;
#pragma unroll
        for (int s = 0; s < 2; ++s)
            aoff[m][s] = row*128 + (((s*4 + fg) ^ (row & 7)) * 16);
    }
#pragma unroll
    for (int n = 0; n < 4; ++n) {
        int row = wn*64 + n*16 + fr;
#pragma unroll
        for (int s = 0; s < 2; ++s)
            boff[n][s] = row*128 + (((s*4 + fg) ^ (row & 7)) * 16);
    }
    const char* Asc = (const char*)As;
    const char* Bsc = (const char*)Bs;

    f4v acc[4][4];
#pragma unroll
    for (int m = 0; m < 4; ++m)
#pragma unroll
        for (int n = 0; n < 4; ++n) { f4v z4 = {0.f,0.f,0.f,0.f}; acc[m][n] = z4; }

    for (int k0 = 0; k0 < K; k0 += 64) {
        if (AM == 1) {
            const unsigned short* Ab = (const unsigned short*)Asrc;
#pragma unroll
            for (int i2 = 0; i2 < 4; ++i2) {
                int row = ar0 + i2*8 + alr;
                int ss = alj ^ alr;
                const char* gp = (const char*)(Ab + (size_t)(m0+row)*lda + k0) + ss*16;
                gload16(gp, (void*)((char*)As + (ar0 + i2*8)*128));
            }
        } else {
            const float* src = (const float*)Asrc + (size_t)(m0+rr)*lda + k0 + kh*32;
            float4 v[8];
#pragma unroll
            for (int i2 = 0; i2 < 8; ++i2) v[i2] = ((const float4*)src)[i2];
#pragma unroll
            for (int qd = 0; qd < 4; ++qd) {
                uint4 w;
                w.x = pk2(v[2*qd].x, v[2*qd].y);   w.y = pk2(v[2*qd].z, v[2*qd].w);
                w.z = pk2(v[2*qd+1].x, v[2*qd+1].y); w.w = pk2(v[2*qd+1].z, v[2*qd+1].w);
                int j = (kh*4 + qd) ^ (rr & 7);
                *(uint4*)((char*)As + rr*128 + j*16) = w;
            }
        }
        if (BM == 1) {
            const unsigned short* Bb = (const unsigned short*)Bsrc;
#pragma unroll
            for (int i2 = 0; i2 < 4; ++i2) {
                int row = ar0 + i2*8 + alr;
                int ss = alj ^ alr;
                const char* gp = (const char*)(Bb + (size_t)(n0+row)*K + k0) + ss*16;
                gload16(gp, (void*)((char*)Bs + (ar0 + i2*8)*128));
            }
        } else {
            const float* src = (const float*)Bsrc + (size_t)(n0+rr)*K + k0 + kh*32;
            float4 v[8];
#pragma unroll
            for (int i2 = 0; i2 < 8; ++i2) v[i2] = ((const float4*)src)[i2];
#pragma unroll
            for (int qd = 0; qd < 4; ++qd) {
                uint4 w;
                w.x = pk2(v[2*qd].x, v[2*qd].y);   w.y = pk2(v[2*qd].z, v[2*qd].w);
                w.z = pk2(v[2*qd+1].x, v[2*qd+1].y); w.w = pk2(v[2*qd+1].z, v[2*qd+1].w);
                int j = (kh*4 + qd) ^ (rr & 7);
                *(uint4*)((char*)Bs + rr*128 + j*16) = w;
            }
        }
        __syncthreads();
#pragma unroll
        for (int s = 0; s < 2; ++s) {
            s8v a[4], b[4];
#pragma unroll
            for (int m = 0; m < 4; ++m) a[m] = *(const s8v*)(Asc + aoff[m][s]);
#pragma unroll
            for (int n = 0; n < 4; ++n) b[n] = *(const s8v*)(Bsc + boff[n][s]);
#pragma unroll
            for (int m = 0; m < 4; ++m)
#pragma unroll
                for (int n = 0; n < 4; ++n)
                    acc[m][n] = __builtin_amdgcn_mfma_f32_16x16x32_bf16(a[m], b[n], acc[m][n], 0, 0, 0);
        }
        __syncthreads();
    }

    // ---- epilogue; C/D: col = lane&15, row = (lane>>4)*4 + j  [m89] ----
    const int cr = (lane >> 4) * 4;
    const int cc = lane & 15;
#pragma unroll
    for (int m = 0; m < 4; ++m) {
        const int grow0 = m0 + wm*64 + m*16 + cr;
#pragma unroll
        for (int n = 0; n < 4; ++n) {
            const int colb = n0 + wn*64 + n*16;   // wave-uniform -> plane uniform
            const int gcol = colb + cc;
            if (EPI == 0) {
#pragma unroll
                for (int j = 0; j < 4; ++j)
                    Cf[(size_t)(grow0+j)*N + gcol] = acc[m][n][j];
            } else if (EPI == 1) {
                unsigned short* dst = (colb < H_) ? C0 : C1;
                const int pc = gcol & (H_-1);
#pragma unroll
                for (int j = 0; j < 4; ++j)
                    dst[(size_t)(grow0+j)*H_ + pc] = f2bf(acc[m][n][j]);
            } else {   // EPI == 2: raw f|i|o planes
                const int plane = colb >> 11;
                unsigned short* dst = (plane == 0) ? C0 : ((plane == 1) ? C1 : C2);
                const int pc = gcol & (H_-1);
#pragma unroll
                for (int j = 0; j < 4; ++j)
                    dst[(size_t)(grow0+j)*H_ + pc] = f2bf(acc[m][n][j]);
            }
        }
    }
}

// ============ causal depthwise conv K=4, vec8 ============
__global__ __launch_bounds__(256)
void conv8(const unsigned short* __restrict__ u, const float* __restrict__ Wc,
           const float* __restrict__ bc, unsigned short* __restrict__ v)
{
    size_t i8 = ((size_t)blockIdx.x*256 + threadIdx.x) * 8;
    int h = (int)(i8 % H_);
    size_t bt = i8 / H_;
    int t = (int)(bt % T_);
    float w[8][4], acc[8];
#pragma unroll
    for (int j = 0; j < 8; ++j) {
        float4 wr = *(const float4*)(Wc + (h+j)*4);
        w[j][0]=wr.x; w[j][1]=wr.y; w[j][2]=wr.z; w[j][3]=wr.w;
        acc[j] = bc[h+j];
    }
    const unsigned short* up = u + bt*H_ + h;
#pragma unroll
    for (int k = 0; k < 4; ++k) {
        int dt = 3 - k;
        if (t >= dt) {
            uint4 r = *(const uint4*)(up - (size_t)dt*H_);
            float e[8]; up8(r, e);
#pragma unroll
            for (int j = 0; j < 8; ++j) acc[j] = fmaf(e[j], w[j][k], acc[j]);
        }
    }
    uint4 o;
    o.x = pk2(acc[0],acc[1]); o.y = pk2(acc[2],acc[3]);
    o.z = pk2(acc[4],acc[5]); o.w = pk2(acc[6],acc[7]);
    *(uint4*)(v + i8) = o;
}

// ============ scan pass 1: per-chunk fold, transforms fused ============
// grid (H/1024, NC, B), 128 threads (vec8): 1024 blocks -> 4/CU TLP.
__global__ __launch_bounds__(128)
void scan_chunk8(const unsigned short* __restrict__ fp, const unsigned short* __restrict__ ip,
                 const unsigned short* __restrict__ vp,
                 const float* __restrict__ bg, const float* __restrict__ app,
                 float* __restrict__ cA, float* __restrict__ cB, int CT)
{
    int hh = (blockIdx.x * 128 + threadIdx.x) * 8;
    int c = blockIdx.y, b = blockIdx.z;
    const float ap = fmaxf(app[0], 0.f);
    const bool ap1 = (ap == 1.0f);
    float bf[8], bi[8];
#pragma unroll
    for (int j = 0; j < 8; ++j) { bf[j] = bg[hh+j]; bi[j] = bg[H_+hh+j]; }
    size_t base = ((size_t)b*T_ + (size_t)c*CT)*H_ + hh;
    float A[8], Bv[8];
#pragma unroll
    for (int j=0;j<8;++j){ A[j]=1.f; Bv[j]=0.f; }
    for (int t = 0; t < CT; ++t) {
        float f[8], i8a[8], v[8];
        up8(*(const uint4*)(fp+base), f);
        up8(*(const uint4*)(ip+base), i8a);
        up8(*(const uint4*)(vp+base), v);
#pragma unroll
        for (int j=0;j<8;++j){
            float s = 1.f/(1.f+expf(f[j]+bf[j]));          // sigmoid(-(f+bf))
            float a = ap1 ? s : powf(s, ap);
            float xin = v[j] / (1.f+expf(-(i8a[j]+bi[j]))); // sigm(i+bi)*v
            A[j]*=a; Bv[j]=fmaf(a,Bv[j],xin);
        }
        base += H_;
    }
    size_t ci = ((size_t)b*gridDim.y + c)*H_ + hh;
    *(float4*)(cA+ci)   = (float4){A[0],A[1],A[2],A[3]};
    *(float4*)(cA+ci+4) = (float4){A[4],A[5],A[6],A[7]};
    *(float4*)(cB+ci)   = (float4){Bv[0],Bv[1],Bv[2],Bv[3]};
    *(float4*)(cB+ci+4) = (float4){Bv[4],Bv[5],Bv[6],Bv[7]};
}

// ============ scan pass 2: sequential carry, scalar (B*H threads, 32 blocks) ====
__global__ __launch_bounds__(256)
void scan_carry1(const float* __restrict__ cA, const float* __restrict__ cB,
                 float* __restrict__ cin, int NC)
{
    int idx = blockIdx.x*256 + threadIdx.x;   // B*H total
    int b  = idx >> 11;                       // / H_
    int hh = idx & (H_-1);
    float h = 0.f;
    for (int c = 0; c < NC; ++c) {
        size_t ci = ((size_t)b*NC + c)*H_ + hh;
        cin[ci] = h;
        h = fmaf(cA[ci], h, cB[ci]);
    }
}

// ============ scan pass 3: re-scan + full gate math; z written into v ====
__global__ __launch_bounds__(128)
void scan_apply8(const unsigned short* __restrict__ fp, const unsigned short* __restrict__ ip,
                 const unsigned short* __restrict__ op, const unsigned short* __restrict__ ga,
                 unsigned short* __restrict__ vz,   // v plane read, z written in place
                 const float* __restrict__ bg, const float* __restrict__ app,
                 const float* __restrict__ cin, int CT)
{
    int hh = (blockIdx.x * 128 + threadIdx.x) * 8;
    int c = blockIdx.y, b = blockIdx.z;
    const float ap = fmaxf(app[0], 0.f);
    const bool ap1 = (ap == 1.0f);
    float bf[8], bi[8], bo[8];
#pragma unroll
    for (int j = 0; j < 8; ++j) {
        bf[j] = bg[hh+j]; bi[j] = bg[H_+hh+j]; bo[j] = bg[2*H_+hh+j];
    }
    size_t base = ((size_t)b*T_ + (size_t)c*CT)*H_ + hh;
    size_t ci = ((size_t)b*gridDim.y + c)*H_ + hh;
    float h[8];
    {
        float4 h0 = *(const float4*)(cin+ci), h1 = *(const float4*)(cin+ci+4);
        h[0]=h0.x; h[1]=h0.y; h[2]=h0.z; h[3]=h0.w;
        h[4]=h1.x; h[5]=h1.y; h[6]=h1.z; h[7]=h1.w;
    }
    for (int t = 0; t < CT; ++t) {
        float f[8], i8a[8], o8[8], g[8], v[8], zo[8];
        up8(*(const uint4*)(fp+base), f);
        up8(*(const uint4*)(ip+base), i8a);
        up8(*(const uint4*)(op+base), o8);
        up8(*(const uint4*)(ga+base), g);
        up8(*(const uint4*)(vz+base), v);
#pragma unroll
        for (int j=0;j<8;++j) {
            float s = 1.f/(1.f+expf(f[j]+bf[j]));
            float a = ap1 ? s : powf(s, ap);
            float xin = v[j] / (1.f+expf(-(i8a[j]+bi[j])));
            h[j] = fmaf(a, h[j], xin);
            float so = 1.f/(1.f+expf(-(o8[j]+bo[j])));
            float ge = 0.5f*g[j]*(1.f+erff(g[j]*0.70710678118654752f));
            zo[j] = ge * so * h[j];
        }
        uint4 o;
        o.x = pk2(zo[0],zo[1]); o.y = pk2(zo[2],zo[3]);
        o.z = pk2(zo[4],zo[5]); o.w = pk2(zo[6],zo[7]);
        *(uint4*)(vz + base) = o;
        base += H_;
    }
}

__global__ void zero_out(float* __restrict__ out, size_t n)
{
    for (size_t i = (size_t)blockIdx.x*256 + threadIdx.x; i < n; i += (size_t)gridDim.x*256)
        out[i] = 0.f;
}

extern "C" void kernel_launch(void* const* d_in, const int* in_sizes, int n_in,
                              void* d_out, int out_size, void* d_ws, size_t ws_size,
                              hipStream_t stream)
{
    const float* x       = (const float*)d_in[0];
    const float* W_in    = (const float*)d_in[1];
    const float* W_conv  = (const float*)d_in[2];
    const float* b_conv  = (const float*)d_in[3];
    const float* W_gates = (const float*)d_in[4];
    const float* b_gates = (const float*)d_in[5];
    const float* W_out   = (const float*)d_in[6];
    const float* alpha_p = (const float*)d_in[7];
    float* out = (float*)d_out;

    const size_t plane = (size_t)B_ * T_ * H_;   // 16.78M elems
    // planes: gate | f(=u slot) | v(->z) | i | o
    unsigned short* gate = (unsigned short*)d_ws;
    unsigned short* fpl  = gate + plane;   // u during GEMM1/conv, then raw f
    unsigned short* v    = fpl + plane;    // v, then z in place
    unsigned short* ipl  = v + plane;
    unsigned short* opl  = ipl + plane;
    char* R = (char*)(opl + plane);        // time-shared region

    const size_t x_elems  = (size_t)B_*T_*D_;
    const size_t wg_elems = (size_t)3*H_*H_;
    const size_t wi_elems = (size_t)2*H_*D_;
    const size_t wo_elems = (size_t)D_*H_;
    const int NCF = 128;                              // CT=16
    const size_t carry_b = 3*(size_t)B_*NCF*H_*4;     // 12.58 MB
    const size_t Rneed = x_elems*2 > carry_b + wo_elems*2 ? x_elems*2 : carry_b + wo_elems*2;
    const size_t need_fast = 5*plane*2 + Rneed;

    if (ws_size >= need_fast && (size_t)out_size*4 >= (wg_elems + wi_elems)*2) {
        // ---------- fast path ----------
        unsigned short* wgb  = (unsigned short*)d_out;      // dead before GEMM3 writes out
        unsigned short* winb = wgb + wg_elems;
        unsigned short* xb   = (unsigned short*)R;          // live through GEMM1
        float* cAp  = (float*)R;                            // written after GEMM1
        float* cBp  = cAp + (size_t)B_*NCF*H_;
        float* cinp = cBp + (size_t)B_*NCF*H_;
        unsigned short* woutb = (unsigned short*)(cinp + (size_t)B_*NCF*H_);
        const int CT = T_ / NCF;

        cvt8<<<(unsigned)(x_elems/2048),  256, 0, stream>>>(x, xb);
        cvt8<<<(unsigned)(wi_elems/2048), 256, 0, stream>>>(W_in, winb);
        cvt8<<<(unsigned)(wg_elems/2048), 256, 0, stream>>>(W_gates, wgb);
        // GEMM1: gate|u = x @ W_in^T
        mgemm<1,1,1><<<dim3(32,64), 256, 0, stream>>>(
            xb, D_, winb, D_, 2*H_, gate, fpl, nullptr, nullptr);
        conv8<<<(unsigned)(plane/8/256), 256, 0, stream>>>(fpl, W_conv, b_conv, v);
        cvt8<<<(unsigned)(wo_elems/2048), 256, 0, stream>>>(W_out, woutb);  // xb dead
        // GEMM2: raw f|i|o = v @ W_gates^T   (f overwrites u slot)
        mgemm<1,1,2><<<dim3(48,64), 256, 0, stream>>>(
            v, H_, wgb, H_, 3*H_, fpl, ipl, opl, nullptr);
        scan_chunk8<<<dim3(2,NCF,B_), 128, 0, stream>>>(fpl, ipl, v, b_gates, alpha_p, cAp, cBp, CT);
        scan_carry1<<<(B_*H_)/256, 256, 0, stream>>>(cAp, cBp, cinp, NCF);
        scan_apply8<<<dim3(2,NCF,B_), 128, 0, stream>>>(fpl, ipl, opl, gate, v, b_gates, alpha_p, cinp, CT);
        // GEMM3: out = z @ W_out^T
        mgemm<1,1,0><<<dim3(8,64), 256, 0, stream>>>(
            v, H_, woutb, H_, D_, nullptr, nullptr, nullptr, out);
        return;
    }

    // ---------- fallback (same scheme, fp32 sources reg-staged) ----------
    float* cAp = (float*)R;
    int NC = 128;
    if (ws_size < 5*plane*2 + 3*(size_t)B_*128*H_*4) {
        NC = 16;
        if (ws_size < 5*plane*2 + 3*(size_t)B_*16*H_*4) {
            zero_out<<<2048, 256, 0, stream>>>(out, (size_t)out_size);
            return;
        }
    }
    const int CT = T_ / NC;
    float* cBp  = cAp + (size_t)B_*NC*H_;
    float* cinp = cBp + (size_t)B_*NC*H_;

    mgemm<0,0,1><<<dim3(32,64), 256, 0, stream>>>(
        x, D_, W_in, D_, 2*H_, gate, fpl, nullptr, nullptr);
    conv8<<<(unsigned)(plane/8/256), 256, 0, stream>>>(fpl, W_conv, b_conv, v);
    mgemm<1,0,2><<<dim3(48,64), 256, 0, stream>>>(
        v, H_, W_gates, H_, 3*H_, fpl, ipl, opl, nullptr);
    scan_chunk8<<<dim3(2,NC,B_), 128, 0, stream>>>(fpl, ipl, v, b_gates, alpha_p, cAp, cBp, CT);
    scan_carry1<<<(B_*H_)/256, 256, 0, stream>>>(cAp, cBp, cinp, NC);
    scan_apply8<<<dim3(2,NC,B_), 128, 0, stream>>>(fpl, ipl, opl, gate, v, b_gates, alpha_p, cinp, CT);
    mgemm<1,0,0><<<dim3(8,64), 256, 0, stream>>>(
        v, H_, W_out, H_, D_, nullptr, nullptr, nullptr, out);
}

// Round 12
// 562.657 us; speedup vs baseline: 7.2133x; 1.0263x over previous
//
#include <hip/hip_runtime.h>
#include <hip/hip_bf16.h>
#include <cstdint>
#include <cstddef>

#define B_ 4
#define T_ 2048
#define D_ 1024
#define H_ 2048

typedef __attribute__((ext_vector_type(8))) short s8v;   // 8 bf16 (4 VGPR)
typedef __attribute__((ext_vector_type(4))) float f4v;   // 4 f32 acc

__device__ __forceinline__ float bflo(unsigned int u){ union{unsigned int i;float f;}c; c.i=u<<16; return c.f; }
__device__ __forceinline__ float bfhi(unsigned int u){ union{unsigned int i;float f;}c; c.i=u&0xffff0000u; return c.f; }
__device__ __forceinline__ unsigned short f2bf(float f){
    __hip_bfloat16 h = __float2bfloat16(f);
    union { __hip_bfloat16 h; unsigned short u; } c; c.h = h; return c.u;
}
__device__ __forceinline__ unsigned int pk2(float lo, float hi){
    return (unsigned int)f2bf(lo) | ((unsigned int)f2bf(hi) << 16);
}
__device__ __forceinline__ void up8(uint4 w, float* r){
    r[0]=bflo(w.x); r[1]=bfhi(w.x); r[2]=bflo(w.y); r[3]=bfhi(w.y);
    r[4]=bflo(w.z); r[5]=bfhi(w.z); r[6]=bflo(w.w); r[7]=bfhi(w.w);
}

__device__ __forceinline__ void gload16(const void* g, void* l){
    __builtin_amdgcn_global_load_lds(
        (const __attribute__((address_space(1))) unsigned int*)g,
        (__attribute__((address_space(3))) unsigned int*)l, 16, 0, 0);
}

__device__ __forceinline__ void cvt_unit(const float* s, unsigned short* d, size_t i){
    float4 a = *(const float4*)(s+i), b = *(const float4*)(s+i+4);
    uint4 o; o.x=pk2(a.x,a.y); o.y=pk2(a.z,a.w); o.z=pk2(b.x,b.y); o.w=pk2(b.z,b.w);
    *(uint4*)(d+i)=o;
}

// ============ merged fp32->bf16 conversion for 3 arrays (vec8 units) ============
__global__ __launch_bounds__(256)
void cvt3(const float* __restrict__ s0, unsigned short* __restrict__ d0, unsigned n0,
          const float* __restrict__ s1, unsigned short* __restrict__ d1, unsigned n1,
          const float* __restrict__ s2, unsigned short* __restrict__ d2, unsigned n2)
{
    unsigned u = blockIdx.x*256 + threadIdx.x;
    if (u < n0)           { cvt_unit(s0, d0, (size_t)u*8); }
    else if (u < n0+n1)   { cvt_unit(s1, d1, (size_t)(u-n0)*8); }
    else if (u < n0+n1+n2){ cvt_unit(s2, d2, (size_t)(u-n0-n1)*8); }
}

// ============ causal depthwise conv K=4 (vec8) fused with W_out cvt ============
__global__ __launch_bounds__(256)
void conv_cvt(const unsigned short* __restrict__ u, const float* __restrict__ Wc,
              const float* __restrict__ bc, unsigned short* __restrict__ v,
              unsigned nconv,
              const float* __restrict__ ws, unsigned short* __restrict__ wd, unsigned ncvt)
{
    unsigned tu = blockIdx.x*256 + threadIdx.x;
    if (tu < nconv) {
        size_t i8 = (size_t)tu * 8;
        int h = (int)(i8 % H_);
        size_t bt = i8 / H_;
        int t = (int)(bt % T_);
        float w[8][4], acc[8];
#pragma unroll
        for (int j = 0; j < 8; ++j) {
            float4 wr = *(const float4*)(Wc + (h+j)*4);
            w[j][0]=wr.x; w[j][1]=wr.y; w[j][2]=wr.z; w[j][3]=wr.w;
            acc[j] = bc[h+j];
        }
        const unsigned short* up = u + bt*H_ + h;
#pragma unroll
        for (int k = 0; k < 4; ++k) {
            int dt = 3 - k;
            if (t >= dt) {
                uint4 r = *(const uint4*)(up - (size_t)dt*H_);
                float e[8]; up8(r, e);
#pragma unroll
                for (int j = 0; j < 8; ++j) acc[j] = fmaf(e[j], w[j][k], acc[j]);
            }
        }
        uint4 o;
        o.x = pk2(acc[0],acc[1]); o.y = pk2(acc[2],acc[3]);
        o.z = pk2(acc[4],acc[5]); o.w = pk2(acc[6],acc[7]);
        *(uint4*)(v + i8) = o;
    } else if (tu < nconv + ncvt) {
        cvt_unit(ws, wd, (size_t)(tu - nconv)*8);
    }
}

// ======================================================================
// 128x128 MFMA GEMM, BK=64, 4 waves, 16KB-LDS-x2. r11-verified: GEMM2 =
// 226us = 912 TF = the m97-structure ceiling (MfmaUtil 42%); L2-blocked
// XCD mapping (FETCH 772->261MB). UNCHANGED from r11.
// ======================================================================
template<int AM, int BM, int EPI>
__global__ __launch_bounds__(256)
void mgemm(const void* __restrict__ Asrc, int lda,
           const void* __restrict__ Bsrc, int K, int N,
           unsigned short* __restrict__ C0, unsigned short* __restrict__ C1,
           unsigned short* __restrict__ C2, float* __restrict__ Cf)
{
    __shared__ unsigned short As[128*64];
    __shared__ unsigned short Bs[128*64];
    const int tid = threadIdx.x;
    const int lane = tid & 63;
    const int wid = tid >> 6;

    const int nxb = gridDim.x;                 // N/128
    const int orig = blockIdx.y * nxb + blockIdx.x;
    const int xcd = orig & 7;
    const int i = orig >> 3;
    const int gsz = nxb << 2;
    const int g = i / gsz;
    const int r = i - g * gsz;
    const int n0 = (r >> 2) * 128;
    const int m0 = (xcd * 8 + g * 4 + (r & 3)) * 128;

    const int ar0 = wid * 32;
    const int alr = lane >> 3;
    const int alj = lane & 7;
    const int rr = tid >> 1;
    const int kh = tid & 1;

    const int wm = wid >> 1, wn = wid & 1;
    const int fr = lane & 15, fg = lane >> 4;
    int aoff[4][2], boff[4][2];
#pragma unroll
    for (int m = 0; m < 4; ++m) {
        int row = wm*64 + m*16 + fr;
#pragma unroll
        for (int s = 0; s < 2; ++s)
            aoff[m][s] = row*128 + (((s*4 + fg) ^ (row & 7)) * 16);
    }
#pragma unroll
    for (int n = 0; n < 4; ++n) {
        int row = wn*64 + n*16 + fr;
#pragma unroll
        for (int s = 0; s < 2; ++s)
            boff[n][s] = row*128 + (((s*4 + fg) ^ (row & 7)) * 16);
    }
    const char* Asc = (const char*)As;
    const char* Bsc = (const char*)Bs;

    f4v acc[4][4];
#pragma unroll
    for (int m = 0; m < 4; ++m)
#pragma unroll
        for (int n = 0; n < 4; ++n) { f4v z4 = {0.f,0.f,0.f,0.f}; acc[m][n] = z4; }

    for (int k0 = 0; k0 < K; k0 += 64) {
        if (AM == 1) {
            const unsigned short* Ab = (const unsigned short*)Asrc;
#pragma unroll
            for (int i2 = 0; i2 < 4; ++i2) {
                int row = ar0 + i2*8 + alr;
                int ss = alj ^ alr;
                const char* gp = (const char*)(Ab + (size_t)(m0+row)*lda + k0) + ss*16;
                gload16(gp, (void*)((char*)As + (ar0 + i2*8)*128));
            }
        } else {
            const float* src = (const float*)Asrc + (size_t)(m0+rr)*lda + k0 + kh*32;
            float4 v[8];
#pragma unroll
            for (int i2 = 0; i2 < 8; ++i2) v[i2] = ((const float4*)src)[i2];
#pragma unroll
            for (int qd = 0; qd < 4; ++qd) {
                uint4 w;
                w.x = pk2(v[2*qd].x, v[2*qd].y);   w.y = pk2(v[2*qd].z, v[2*qd].w);
                w.z = pk2(v[2*qd+1].x, v[2*qd+1].y); w.w = pk2(v[2*qd+1].z, v[2*qd+1].w);
                int j = (kh*4 + qd) ^ (rr & 7);
                *(uint4*)((char*)As + rr*128 + j*16) = w;
            }
        }
        if (BM == 1) {
            const unsigned short* Bb = (const unsigned short*)Bsrc;
#pragma unroll
            for (int i2 = 0; i2 < 4; ++i2) {
                int row = ar0 + i2*8 + alr;
                int ss = alj ^ alr;
                const char* gp = (const char*)(Bb + (size_t)(n0+row)*K + k0) + ss*16;
                gload16(gp, (void*)((char*)Bs + (ar0 + i2*8)*128));
            }
        } else {
            const float* src = (const float*)Bsrc + (size_t)(n0+rr)*K + k0 + kh*32;
            float4 v[8];
#pragma unroll
            for (int i2 = 0; i2 < 8; ++i2) v[i2] = ((const float4*)src)[i2];
#pragma unroll
            for (int qd = 0; qd < 4; ++qd) {
                uint4 w;
                w.x = pk2(v[2*qd].x, v[2*qd].y);   w.y = pk2(v[2*qd].z, v[2*qd].w);
                w.z = pk2(v[2*qd+1].x, v[2*qd+1].y); w.w = pk2(v[2*qd+1].z, v[2*qd+1].w);
                int j = (kh*4 + qd) ^ (rr & 7);
                *(uint4*)((char*)Bs + rr*128 + j*16) = w;
            }
        }
        __syncthreads();
#pragma unroll
        for (int s = 0; s < 2; ++s) {
            s8v a[4], b[4];
#pragma unroll
            for (int m = 0; m < 4; ++m) a[m] = *(const s8v*)(Asc + aoff[m][s]);
#pragma unroll
            for (int n = 0; n < 4; ++n) b[n] = *(const s8v*)(Bsc + boff[n][s]);
#pragma unroll
            for (int m = 0; m < 4; ++m)
#pragma unroll
                for (int n = 0; n < 4; ++n)
                    acc[m][n] = __builtin_amdgcn_mfma_f32_16x16x32_bf16(a[m], b[n], acc[m][n], 0, 0, 0);
        }
        __syncthreads();
    }

    const int cr = (lane >> 4) * 4;
    const int cc = lane & 15;
#pragma unroll
    for (int m = 0; m < 4; ++m) {
        const int grow0 = m0 + wm*64 + m*16 + cr;
#pragma unroll
        for (int n = 0; n < 4; ++n) {
            const int colb = n0 + wn*64 + n*16;
            const int gcol = colb + cc;
            if (EPI == 0) {
#pragma unroll
                for (int j = 0; j < 4; ++j)
                    Cf[(size_t)(grow0+j)*N + gcol] = acc[m][n][j];
            } else if (EPI == 1) {
                unsigned short* dst = (colb < H_) ? C0 : C1;
                const int pc = gcol & (H_-1);
#pragma unroll
                for (int j = 0; j < 4; ++j)
                    dst[(size_t)(grow0+j)*H_ + pc] = f2bf(acc[m][n][j]);
            } else {
                const int plane = colb >> 11;
                unsigned short* dst = (plane == 0) ? C0 : ((plane == 1) ? C1 : C2);
                const int pc = gcol & (H_-1);
#pragma unroll
                for (int j = 0; j < 4; ++j)
                    dst[(size_t)(grow0+j)*H_ + pc] = f2bf(acc[m][n][j]);
            }
        }
    }
}

// ============ scan pass 1: per-chunk fold, CT compile-time (full unroll) ====
template<int CT>
__global__ __launch_bounds__(128)
void scan_chunk8(const unsigned short* __restrict__ fp, const unsigned short* __restrict__ ip,
                 const unsigned short* __restrict__ vp,
                 const float* __restrict__ bg, const float* __restrict__ app,
                 float* __restrict__ cA, float* __restrict__ cB)
{
    int hh = (blockIdx.x * 128 + threadIdx.x) * 8;
    int c = blockIdx.y, b = blockIdx.z;
    const float ap = fmaxf(app[0], 0.f);
    const bool ap1 = (ap == 1.0f);
    float bf[8], bi[8];
#pragma unroll
    for (int j = 0; j < 8; ++j) { bf[j] = bg[hh+j]; bi[j] = bg[H_+hh+j]; }
    size_t base = ((size_t)b*T_ + (size_t)c*CT)*H_ + hh;
    float A[8], Bv[8];
#pragma unroll
    for (int j=0;j<8;++j){ A[j]=1.f; Bv[j]=0.f; }
#pragma unroll 4
    for (int t = 0; t < CT; ++t) {
        float f[8], i8a[8], v[8];
        up8(*(const uint4*)(fp+base), f);
        up8(*(const uint4*)(ip+base), i8a);
        up8(*(const uint4*)(vp+base), v);
#pragma unroll
        for (int j=0;j<8;++j){
            float s = 1.f/(1.f+expf(f[j]+bf[j]));
            float a = ap1 ? s : powf(s, ap);
            float xin = v[j] / (1.f+expf(-(i8a[j]+bi[j])));
            A[j]*=a; Bv[j]=fmaf(a,Bv[j],xin);
        }
        base += H_;
    }
    size_t ci = ((size_t)b*gridDim.y + c)*H_ + hh;
    *(float4*)(cA+ci)   = (float4){A[0],A[1],A[2],A[3]};
    *(float4*)(cA+ci+4) = (float4){A[4],A[5],A[6],A[7]};
    *(float4*)(cB+ci)   = (float4){Bv[0],Bv[1],Bv[2],Bv[3]};
    *(float4*)(cB+ci+4) = (float4){Bv[4],Bv[5],Bv[6],Bv[7]};
}

// ============ scan pass 2: wave-parallel 16-lane segmented scan ============
// NC = CPL*16 chunks. Lane sub folds chunks [sub*CPL, sub*CPL+CPL), 4-step
// Hillis-Steele compose across the 16-lane segment, re-emit prefixes.
// vec4 over hh; wave = 16 subs x 4 consecutive hh4-groups -> 64B-coalesced.
template<int CPL>
__global__ __launch_bounds__(256)
void scan_carry16(const float* __restrict__ cA, const float* __restrict__ cB,
                  float* __restrict__ cin)
{
    const int NC = CPL * 16;
    int tg = blockIdx.x*256 + threadIdx.x;      // B*(H/4)*16 total
    int sub = tg & 15;
    int grp = tg >> 4;                          // b*(H/4) + hh/4
    int b = grp / (H_/4);
    int hh = (grp % (H_/4)) * 4;
    float4 ac[CPL], bc4[CPL];
    float4 Ag = {1.f,1.f,1.f,1.f}, Bg = {0.f,0.f,0.f,0.f};
#pragma unroll
    for (int k = 0; k < CPL; ++k) {
        size_t ci = ((size_t)b*NC + sub*CPL + k)*H_ + hh;
        float4 a = *(const float4*)(cA+ci);
        float4 x = *(const float4*)(cB+ci);
        ac[k] = a; bc4[k] = x;
        Bg.x = fmaf(a.x,Bg.x,x.x); Bg.y = fmaf(a.y,Bg.y,x.y);
        Bg.z = fmaf(a.z,Bg.z,x.z); Bg.w = fmaf(a.w,Bg.w,x.w);
        Ag.x *= a.x; Ag.y *= a.y; Ag.z *= a.z; Ag.w *= a.w;
    }
#pragma unroll
    for (int d = 1; d < 16; d <<= 1) {
        float4 Au, Bu;
        Au.x = __shfl_up(Ag.x, d, 16); Au.y = __shfl_up(Ag.y, d, 16);
        Au.z = __shfl_up(Ag.z, d, 16); Au.w = __shfl_up(Ag.w, d, 16);
        Bu.x = __shfl_up(Bg.x, d, 16); Bu.y = __shfl_up(Bg.y, d, 16);
        Bu.z = __shfl_up(Bg.z, d, 16); Bu.w = __shfl_up(Bg.w, d, 16);
        if (sub >= d) {
            Bg.x = fmaf(Ag.x,Bu.x,Bg.x); Bg.y = fmaf(Ag.y,Bu.y,Bg.y);
            Bg.z = fmaf(Ag.z,Bu.z,Bg.z); Bg.w = fmaf(Ag.w,Bu.w,Bg.w);
            Ag.x *= Au.x; Ag.y *= Au.y; Ag.z *= Au.z; Ag.w *= Au.w;
        }
    }
    float4 h;
    h.x = __shfl_up(Bg.x, 1, 16); h.y = __shfl_up(Bg.y, 1, 16);
    h.z = __shfl_up(Bg.z, 1, 16); h.w = __shfl_up(Bg.w, 1, 16);
    if (sub == 0) { h.x=0.f; h.y=0.f; h.z=0.f; h.w=0.f; }
#pragma unroll
    for (int k = 0; k < CPL; ++k) {
        size_t ci = ((size_t)b*NC + sub*CPL + k)*H_ + hh;
        *(float4*)(cin+ci) = h;
        h.x = fmaf(ac[k].x,h.x,bc4[k].x); h.y = fmaf(ac[k].y,h.y,bc4[k].y);
        h.z = fmaf(ac[k].z,h.z,bc4[k].z); h.w = fmaf(ac[k].w,h.w,bc4[k].w);
    }
}

// ============ scan pass 3: re-scan + full gate math; z over v in place ====
template<int CT>
__global__ __launch_bounds__(128)
void scan_apply8(const unsigned short* __restrict__ fp, const unsigned short* __restrict__ ip,
                 const unsigned short* __restrict__ op, const unsigned short* __restrict__ ga,
                 unsigned short* __restrict__ vz,
                 const float* __restrict__ bg, const float* __restrict__ app,
                 const float* __restrict__ cin)
{
    int hh = (blockIdx.x * 128 + threadIdx.x) * 8;
    int c = blockIdx.y, b = blockIdx.z;
    const float ap = fmaxf(app[0], 0.f);
    const bool ap1 = (ap == 1.0f);
    float bf[8], bi[8], bo[8];
#pragma unroll
    for (int j = 0; j < 8; ++j) {
        bf[j] = bg[hh+j]; bi[j] = bg[H_+hh+j]; bo[j] = bg[2*H_+hh+j];
    }
    size_t base = ((size_t)b*T_ + (size_t)c*CT)*H_ + hh;
    size_t ci = ((size_t)b*gridDim.y + c)*H_ + hh;
    float h[8];
    {
        float4 h0 = *(const float4*)(cin+ci), h1 = *(const float4*)(cin+ci+4);
        h[0]=h0.x; h[1]=h0.y; h[2]=h0.z; h[3]=h0.w;
        h[4]=h1.x; h[5]=h1.y; h[6]=h1.z; h[7]=h1.w;
    }
#pragma unroll 4
    for (int t = 0; t < CT; ++t) {
        float f[8], i8a[8], o8[8], g[8], v[8], zo[8];
        up8(*(const uint4*)(fp+base), f);
        up8(*(const uint4*)(ip+base), i8a);
        up8(*(const uint4*)(op+base), o8);
        up8(*(const uint4*)(ga+base), g);
        up8(*(const uint4*)(vz+base), v);
#pragma unroll
        for (int j=0;j<8;++j) {
            float s = 1.f/(1.f+expf(f[j]+bf[j]));
            float a = ap1 ? s : powf(s, ap);
            float xin = v[j] / (1.f+expf(-(i8a[j]+bi[j])));
            h[j] = fmaf(a, h[j], xin);
            float so = 1.f/(1.f+expf(-(o8[j]+bo[j])));
            float ge = 0.5f*g[j]*(1.f+erff(g[j]*0.70710678118654752f));
            zo[j] = ge * so * h[j];
        }
        uint4 o;
        o.x = pk2(zo[0],zo[1]); o.y = pk2(zo[2],zo[3]);
        o.z = pk2(zo[4],zo[5]); o.w = pk2(zo[6],zo[7]);
        *(uint4*)(vz + base) = o;
        base += H_;
    }
}

__global__ void zero_out(float* __restrict__ out, size_t n)
{
    for (size_t i = (size_t)blockIdx.x*256 + threadIdx.x; i < n; i += (size_t)gridDim.x*256)
        out[i] = 0.f;
}

extern "C" void kernel_launch(void* const* d_in, const int* in_sizes, int n_in,
                              void* d_out, int out_size, void* d_ws, size_t ws_size,
                              hipStream_t stream)
{
    const float* x       = (const float*)d_in[0];
    const float* W_in    = (const float*)d_in[1];
    const float* W_conv  = (const float*)d_in[2];
    const float* b_conv  = (const float*)d_in[3];
    const float* W_gates = (const float*)d_in[4];
    const float* b_gates = (const float*)d_in[5];
    const float* W_out   = (const float*)d_in[6];
    const float* alpha_p = (const float*)d_in[7];
    float* out = (float*)d_out;

    const size_t plane = (size_t)B_ * T_ * H_;   // 16.78M elems
    unsigned short* gate = (unsigned short*)d_ws;
    unsigned short* fpl  = gate + plane;   // u during GEMM1/conv, then raw f
    unsigned short* v    = fpl + plane;    // v, then z in place
    unsigned short* ipl  = v + plane;
    unsigned short* opl  = ipl + plane;
    char* R = (char*)(opl + plane);        // time-shared region

    const size_t x_elems  = (size_t)B_*T_*D_;
    const size_t wg_elems = (size_t)3*H_*H_;
    const size_t wi_elems = (size_t)2*H_*D_;
    const size_t wo_elems = (size_t)D_*H_;
    const int NCF = 128;                              // CT=16, CPL=8
    const size_t carry_b = 3*(size_t)B_*NCF*H_*4;     // 12.58 MB
    const size_t Rneed = x_elems*2 > carry_b + wo_elems*2 ? x_elems*2 : carry_b + wo_elems*2;
    const size_t need_fast = 5*plane*2 + Rneed;

    if (ws_size >= need_fast && (size_t)out_size*4 >= (wg_elems + wi_elems)*2) {
        // ---------- fast path ----------
        unsigned short* wgb  = (unsigned short*)d_out;      // dead before GEMM3 writes out
        unsigned short* winb = wgb + wg_elems;
        unsigned short* xb   = (unsigned short*)R;          // live through GEMM1
        float* cAp  = (float*)R;                            // written after GEMM1
        float* cBp  = cAp + (size_t)B_*NCF*H_;
        float* cinp = cBp + (size_t)B_*NCF*H_;
        unsigned short* woutb = (unsigned short*)(cinp + (size_t)B_*NCF*H_);

        const unsigned nx = (unsigned)(x_elems/8), nwi = (unsigned)(wi_elems/8),
                       nwg = (unsigned)(wg_elems/8), nwo = (unsigned)(wo_elems/8),
                       ncv = (unsigned)(plane/8);
        // one dispatch converts x, W_in, W_gates
        cvt3<<<(nx+nwi+nwg)/256, 256, 0, stream>>>(x, xb, nx, W_in, winb, nwi, W_gates, wgb, nwg);
        // GEMM1: gate|u = x @ W_in^T
        mgemm<1,1,1><<<dim3(32,64), 256, 0, stream>>>(
            xb, D_, winb, D_, 2*H_, gate, fpl, nullptr, nullptr);
        // conv: u -> v, fused with W_out cvt (xb dead after GEMM1)
        conv_cvt<<<(ncv+nwo)/256, 256, 0, stream>>>(fpl, W_conv, b_conv, v, ncv, W_out, woutb, nwo);
        // GEMM2: raw f|i|o = v @ W_gates^T
        mgemm<1,1,2><<<dim3(48,64), 256, 0, stream>>>(
            v, H_, wgb, H_, 3*H_, fpl, ipl, opl, nullptr);
        scan_chunk8<16><<<dim3(2,NCF,B_), 128, 0, stream>>>(fpl, ipl, v, b_gates, alpha_p, cAp, cBp);
        scan_carry16<8><<<(B_*(H_/4)*16)/256, 256, 0, stream>>>(cAp, cBp, cinp);
        scan_apply8<16><<<dim3(2,NCF,B_), 128, 0, stream>>>(fpl, ipl, opl, gate, v, b_gates, alpha_p, cinp);
        // GEMM3: out = z @ W_out^T
        mgemm<1,1,0><<<dim3(8,64), 256, 0, stream>>>(
            v, H_, woutb, H_, D_, nullptr, nullptr, nullptr, out);
        return;
    }

    // ---------- fallback (fp32 sources reg-staged; NC=16) ----------
    float* cAp = (float*)R;
    if (ws_size < 5*plane*2 + 3*(size_t)B_*16*H_*4) {
        zero_out<<<2048, 256, 0, stream>>>(out, (size_t)out_size);
        return;
    }
    const int NC = 16;   // CT = 128, CPL = 1
    float* cBp  = cAp + (size_t)B_*NC*H_;
    float* cinp = cBp + (size_t)B_*NC*H_;

    mgemm<0,0,1><<<dim3(32,64), 256, 0, stream>>>(
        x, D_, W_in, D_, 2*H_, gate, fpl, nullptr, nullptr);
    conv_cvt<<<(unsigned)(plane/8/256), 256, 0, stream>>>(fpl, W_conv, b_conv, v,
        (unsigned)(plane/8), nullptr, nullptr, 0);
    mgemm<1,0,2><<<dim3(48,64), 256, 0, stream>>>(
        v, H_, W_gates, H_, 3*H_, fpl, ipl, opl, nullptr);
    scan_chunk8<128><<<dim3(2,NC,B_), 128, 0, stream>>>(fpl, ipl, v, b_gates, alpha_p, cAp, cBp);
    scan_carry16<1><<<(B_*(H_/4)*16)/256, 256, 0, stream>>>(cAp, cBp, cinp);
    scan_apply8<128><<<dim3(2,NC,B_), 128, 0, stream>>>(fpl, ipl, opl, gate, v, b_gates, alpha_p, cinp);
    mgemm<1,0,0><<<dim3(8,64), 256, 0, stream>>>(
        v, H_, W_out, H_, D_, nullptr, nullptr, nullptr, out);
}

// Round 13
// 522.590 us; speedup vs baseline: 7.7664x; 1.0767x over previous
//
#include <hip/hip_runtime.h>
#include <hip/hip_bf16.h>
#include <cstdint>
#include <cstddef>

#define B_ 4
#define T_ 2048
#define D_ 1024
#define H_ 2048

typedef __attribute__((ext_vector_type(8))) short s8v;   // 8 bf16 (4 VGPR)
typedef __attribute__((ext_vector_type(4))) float f4v;   // 4 f32 acc

__device__ __forceinline__ float bflo(unsigned int u){ union{unsigned int i;float f;}c; c.i=u<<16; return c.f; }
__device__ __forceinline__ float bfhi(unsigned int u){ union{unsigned int i;float f;}c; c.i=u&0xffff0000u; return c.f; }
__device__ __forceinline__ unsigned short f2bf(float f){
    __hip_bfloat16 h = __float2bfloat16(f);
    union { __hip_bfloat16 h; unsigned short u; } c; c.h = h; return c.u;
}
__device__ __forceinline__ unsigned int pk2(float lo, float hi){
    return (unsigned int)f2bf(lo) | ((unsigned int)f2bf(hi) << 16);
}
__device__ __forceinline__ void up8(uint4 w, float* r){
    r[0]=bflo(w.x); r[1]=bfhi(w.x); r[2]=bflo(w.y); r[3]=bfhi(w.y);
    r[4]=bflo(w.z); r[5]=bfhi(w.z); r[6]=bflo(w.w); r[7]=bfhi(w.w);
}
// fast sigmoid: v_exp + v_rcp (1-2 ulp; ~4 instrs vs ~15 libm).
// error ~1e-7 << bf16 storage error 4e-3 -> absmax unaffected.
__device__ __forceinline__ float fsig(float x){
    return __builtin_amdgcn_rcpf(1.f + __expf(-x));
}

__device__ __forceinline__ void gload16(const void* g, void* l){
    __builtin_amdgcn_global_load_lds(
        (const __attribute__((address_space(1))) unsigned int*)g,
        (__attribute__((address_space(3))) unsigned int*)l, 16, 0, 0);
}

__device__ __forceinline__ void cvt_unit(const float* s, unsigned short* d, size_t i){
    float4 a = *(const float4*)(s+i), b = *(const float4*)(s+i+4);
    uint4 o; o.x=pk2(a.x,a.y); o.y=pk2(a.z,a.w); o.z=pk2(b.x,b.y); o.w=pk2(b.z,b.w);
    *(uint4*)(d+i)=o;
}

// ============ merged fp32->bf16 conversion for 3 arrays (vec8 units) ============
__global__ __launch_bounds__(256)
void cvt3(const float* __restrict__ s0, unsigned short* __restrict__ d0, unsigned n0,
          const float* __restrict__ s1, unsigned short* __restrict__ d1, unsigned n1,
          const float* __restrict__ s2, unsigned short* __restrict__ d2, unsigned n2)
{
    unsigned u = blockIdx.x*256 + threadIdx.x;
    if (u < n0)           { cvt_unit(s0, d0, (size_t)u*8); }
    else if (u < n0+n1)   { cvt_unit(s1, d1, (size_t)(u-n0)*8); }
    else if (u < n0+n1+n2){ cvt_unit(s2, d2, (size_t)(u-n0-n1)*8); }
}

// ============ causal depthwise conv K=4 (vec8) fused with W_out cvt ============
__global__ __launch_bounds__(256)
void conv_cvt(const unsigned short* __restrict__ u, const float* __restrict__ Wc,
              const float* __restrict__ bc, unsigned short* __restrict__ v,
              unsigned nconv,
              const float* __restrict__ ws, unsigned short* __restrict__ wd, unsigned ncvt)
{
    unsigned tu = blockIdx.x*256 + threadIdx.x;
    if (tu < nconv) {
        size_t i8 = (size_t)tu * 8;
        int h = (int)(i8 % H_);
        size_t bt = i8 / H_;
        int t = (int)(bt % T_);
        float w[8][4], acc[8];
#pragma unroll
        for (int j = 0; j < 8; ++j) {
            float4 wr = *(const float4*)(Wc + (h+j)*4);
            w[j][0]=wr.x; w[j][1]=wr.y; w[j][2]=wr.z; w[j][3]=wr.w;
            acc[j] = bc[h+j];
        }
        const unsigned short* up = u + bt*H_ + h;
#pragma unroll
        for (int k = 0; k < 4; ++k) {
            int dt = 3 - k;
            if (t >= dt) {
                uint4 r = *(const uint4*)(up - (size_t)dt*H_);
                float e[8]; up8(r, e);
#pragma unroll
                for (int j = 0; j < 8; ++j) acc[j] = fmaf(e[j], w[j][k], acc[j]);
            }
        }
        uint4 o;
        o.x = pk2(acc[0],acc[1]); o.y = pk2(acc[2],acc[3]);
        o.z = pk2(acc[4],acc[5]); o.w = pk2(acc[6],acc[7]);
        *(uint4*)(v + i8) = o;
    } else if (tu < nconv + ncvt) {
        cvt_unit(ws, wd, (size_t)(tu - nconv)*8);
    }
}

// ======================================================================
// 128x128 MFMA GEMM, BK=64, 4 waves, 16KB-LDS-x2. r11-verified: GEMM2 =
// 227us = 912 TF = the m97-structure ceiling (MfmaUtil 42%); L2-blocked
// XCD mapping (FETCH 772->261MB). UNCHANGED from r11/r12.
// ======================================================================
template<int AM, int BM, int EPI>
__global__ __launch_bounds__(256)
void mgemm(const void* __restrict__ Asrc, int lda,
           const void* __restrict__ Bsrc, int K, int N,
           unsigned short* __restrict__ C0, unsigned short* __restrict__ C1,
           unsigned short* __restrict__ C2, float* __restrict__ Cf)
{
    __shared__ unsigned short As[128*64];
    __shared__ unsigned short Bs[128*64];
    const int tid = threadIdx.x;
    const int lane = tid & 63;
    const int wid = tid >> 6;

    const int nxb = gridDim.x;                 // N/128
    const int orig = blockIdx.y * nxb + blockIdx.x;
    const int xcd = orig & 7;
    const int i = orig >> 3;
    const int gsz = nxb << 2;
    const int g = i / gsz;
    const int r = i - g * gsz;
    const int n0 = (r >> 2) * 128;
    const int m0 = (xcd * 8 + g * 4 + (r & 3)) * 128;

    const int ar0 = wid * 32;
    const int alr = lane >> 3;
    const int alj = lane & 7;
    const int rr = tid >> 1;
    const int kh = tid & 1;

    const int wm = wid >> 1, wn = wid & 1;
    const int fr = lane & 15, fg = lane >> 4;
    int aoff[4][2], boff[4][2];
#pragma unroll
    for (int m = 0; m < 4; ++m) {
        int row = wm*64 + m*16 + fr;
#pragma unroll
        for (int s = 0; s < 2; ++s)
            aoff[m][s] = row*128 + (((s*4 + fg) ^ (row & 7)) * 16);
    }
#pragma unroll
    for (int n = 0; n < 4; ++n) {
        int row = wn*64 + n*16 + fr;
#pragma unroll
        for (int s = 0; s < 2; ++s)
            boff[n][s] = row*128 + (((s*4 + fg) ^ (row & 7)) * 16);
    }
    const char* Asc = (const char*)As;
    const char* Bsc = (const char*)Bs;

    f4v acc[4][4];
#pragma unroll
    for (int m = 0; m < 4; ++m)
#pragma unroll
        for (int n = 0; n < 4; ++n) { f4v z4 = {0.f,0.f,0.f,0.f}; acc[m][n] = z4; }

    for (int k0 = 0; k0 < K; k0 += 64) {
        if (AM == 1) {
            const unsigned short* Ab = (const unsigned short*)Asrc;
#pragma unroll
            for (int i2 = 0; i2 < 4; ++i2) {
                int row = ar0 + i2*8 + alr;
                int ss = alj ^ alr;
                const char* gp = (const char*)(Ab + (size_t)(m0+row)*lda + k0) + ss*16;
                gload16(gp, (void*)((char*)As + (ar0 + i2*8)*128));
            }
        } else {
            const float* src = (const float*)Asrc + (size_t)(m0+rr)*lda + k0 + kh*32;
            float4 v[8];
#pragma unroll
            for (int i2 = 0; i2 < 8; ++i2) v[i2] = ((const float4*)src)[i2];
#pragma unroll
            for (int qd = 0; qd < 4; ++qd) {
                uint4 w;
                w.x = pk2(v[2*qd].x, v[2*qd].y);   w.y = pk2(v[2*qd].z, v[2*qd].w);
                w.z = pk2(v[2*qd+1].x, v[2*qd+1].y); w.w = pk2(v[2*qd+1].z, v[2*qd+1].w);
                int j = (kh*4 + qd) ^ (rr & 7);
                *(uint4*)((char*)As + rr*128 + j*16) = w;
            }
        }
        if (BM == 1) {
            const unsigned short* Bb = (const unsigned short*)Bsrc;
#pragma unroll
            for (int i2 = 0; i2 < 4; ++i2) {
                int row = ar0 + i2*8 + alr;
                int ss = alj ^ alr;
                const char* gp = (const char*)(Bb + (size_t)(n0+row)*K + k0) + ss*16;
                gload16(gp, (void*)((char*)Bs + (ar0 + i2*8)*128));
            }
        } else {
            const float* src = (const float*)Bsrc + (size_t)(n0+rr)*K + k0 + kh*32;
            float4 v[8];
#pragma unroll
            for (int i2 = 0; i2 < 8; ++i2) v[i2] = ((const float4*)src)[i2];
#pragma unroll
            for (int qd = 0; qd < 4; ++qd) {
                uint4 w;
                w.x = pk2(v[2*qd].x, v[2*qd].y);   w.y = pk2(v[2*qd].z, v[2*qd].w);
                w.z = pk2(v[2*qd+1].x, v[2*qd+1].y); w.w = pk2(v[2*qd+1].z, v[2*qd+1].w);
                int j = (kh*4 + qd) ^ (rr & 7);
                *(uint4*)((char*)Bs + rr*128 + j*16) = w;
            }
        }
        __syncthreads();
#pragma unroll
        for (int s = 0; s < 2; ++s) {
            s8v a[4], b[4];
#pragma unroll
            for (int m = 0; m < 4; ++m) a[m] = *(const s8v*)(Asc + aoff[m][s]);
#pragma unroll
            for (int n = 0; n < 4; ++n) b[n] = *(const s8v*)(Bsc + boff[n][s]);
#pragma unroll
            for (int m = 0; m < 4; ++m)
#pragma unroll
                for (int n = 0; n < 4; ++n)
                    acc[m][n] = __builtin_amdgcn_mfma_f32_16x16x32_bf16(a[m], b[n], acc[m][n], 0, 0, 0);
        }
        __syncthreads();
    }

    const int cr = (lane >> 4) * 4;
    const int cc = lane & 15;
#pragma unroll
    for (int m = 0; m < 4; ++m) {
        const int grow0 = m0 + wm*64 + m*16 + cr;
#pragma unroll
        for (int n = 0; n < 4; ++n) {
            const int colb = n0 + wn*64 + n*16;
            const int gcol = colb + cc;
            if (EPI == 0) {
#pragma unroll
                for (int j = 0; j < 4; ++j)
                    Cf[(size_t)(grow0+j)*N + gcol] = acc[m][n][j];
            } else if (EPI == 1) {
                unsigned short* dst = (colb < H_) ? C0 : C1;
                const int pc = gcol & (H_-1);
#pragma unroll
                for (int j = 0; j < 4; ++j)
                    dst[(size_t)(grow0+j)*H_ + pc] = f2bf(acc[m][n][j]);
            } else {
                const int plane = colb >> 11;
                unsigned short* dst = (plane == 0) ? C0 : ((plane == 1) ? C1 : C2);
                const int pc = gcol & (H_-1);
#pragma unroll
                for (int j = 0; j < 4; ++j)
                    dst[(size_t)(grow0+j)*H_ + pc] = f2bf(acc[m][n][j]);
            }
        }
    }
}

// ============ scan pass 1: per-chunk fold (fast sigmoid) ============
template<int CT>
__global__ __launch_bounds__(128)
void scan_chunk8(const unsigned short* __restrict__ fp, const unsigned short* __restrict__ ip,
                 const unsigned short* __restrict__ vp,
                 const float* __restrict__ bg, const float* __restrict__ app,
                 float* __restrict__ cA, float* __restrict__ cB)
{
    int hh = (blockIdx.x * 128 + threadIdx.x) * 8;
    int c = blockIdx.y, b = blockIdx.z;
    const float ap = fmaxf(app[0], 0.f);
    const bool ap1 = (ap == 1.0f);
    float bf[8], bi[8];
#pragma unroll
    for (int j = 0; j < 8; ++j) { bf[j] = bg[hh+j]; bi[j] = bg[H_+hh+j]; }
    size_t base = ((size_t)b*T_ + (size_t)c*CT)*H_ + hh;
    float A[8], Bv[8];
#pragma unroll
    for (int j=0;j<8;++j){ A[j]=1.f; Bv[j]=0.f; }
#pragma unroll 4
    for (int t = 0; t < CT; ++t) {
        float f[8], i8a[8], v[8];
        up8(*(const uint4*)(fp+base), f);
        up8(*(const uint4*)(ip+base), i8a);
        up8(*(const uint4*)(vp+base), v);
#pragma unroll
        for (int j=0;j<8;++j){
            float s = fsig(-(f[j]+bf[j]));                   // sigmoid(-(f+bf))
            float a = ap1 ? s : powf(s, ap);
            float xin = fsig(i8a[j]+bi[j]) * v[j];           // sigm(i+bi)*v
            A[j]*=a; Bv[j]=fmaf(a,Bv[j],xin);
        }
        base += H_;
    }
    size_t ci = ((size_t)b*gridDim.y + c)*H_ + hh;
    *(float4*)(cA+ci)   = (float4){A[0],A[1],A[2],A[3]};
    *(float4*)(cA+ci+4) = (float4){A[4],A[5],A[6],A[7]};
    *(float4*)(cB+ci)   = (float4){Bv[0],Bv[1],Bv[2],Bv[3]};
    *(float4*)(cB+ci+4) = (float4){Bv[4],Bv[5],Bv[6],Bv[7]};
}

// ============ scan pass 2: wave-parallel 16-lane segmented scan ============
template<int CPL>
__global__ __launch_bounds__(256)
void scan_carry16(const float* __restrict__ cA, const float* __restrict__ cB,
                  float* __restrict__ cin)
{
    const int NC = CPL * 16;
    int tg = blockIdx.x*256 + threadIdx.x;      // B*(H/4)*16 total
    int sub = tg & 15;
    int grp = tg >> 4;
    int b = grp / (H_/4);
    int hh = (grp % (H_/4)) * 4;
    float4 ac[CPL], bc4[CPL];
    float4 Ag = {1.f,1.f,1.f,1.f}, Bg = {0.f,0.f,0.f,0.f};
#pragma unroll
    for (int k = 0; k < CPL; ++k) {
        size_t ci = ((size_t)b*NC + sub*CPL + k)*H_ + hh;
        float4 a = *(const float4*)(cA+ci);
        float4 x = *(const float4*)(cB+ci);
        ac[k] = a; bc4[k] = x;
        Bg.x = fmaf(a.x,Bg.x,x.x); Bg.y = fmaf(a.y,Bg.y,x.y);
        Bg.z = fmaf(a.z,Bg.z,x.z); Bg.w = fmaf(a.w,Bg.w,x.w);
        Ag.x *= a.x; Ag.y *= a.y; Ag.z *= a.z; Ag.w *= a.w;
    }
#pragma unroll
    for (int d = 1; d < 16; d <<= 1) {
        float4 Au, Bu;
        Au.x = __shfl_up(Ag.x, d, 16); Au.y = __shfl_up(Ag.y, d, 16);
        Au.z = __shfl_up(Ag.z, d, 16); Au.w = __shfl_up(Ag.w, d, 16);
        Bu.x = __shfl_up(Bg.x, d, 16); Bu.y = __shfl_up(Bg.y, d, 16);
        Bu.z = __shfl_up(Bg.z, d, 16); Bu.w = __shfl_up(Bg.w, d, 16);
        if (sub >= d) {
            Bg.x = fmaf(Ag.x,Bu.x,Bg.x); Bg.y = fmaf(Ag.y,Bu.y,Bg.y);
            Bg.z = fmaf(Ag.z,Bu.z,Bg.z); Bg.w = fmaf(Ag.w,Bu.w,Bg.w);
            Ag.x *= Au.x; Ag.y *= Au.y; Ag.z *= Au.z; Ag.w *= Au.w;
        }
    }
    float4 h;
    h.x = __shfl_up(Bg.x, 1, 16); h.y = __shfl_up(Bg.y, 1, 16);
    h.z = __shfl_up(Bg.z, 1, 16); h.w = __shfl_up(Bg.w, 1, 16);
    if (sub == 0) { h.x=0.f; h.y=0.f; h.z=0.f; h.w=0.f; }
#pragma unroll
    for (int k = 0; k < CPL; ++k) {
        size_t ci = ((size_t)b*NC + sub*CPL + k)*H_ + hh;
        *(float4*)(cin+ci) = h;
        h.x = fmaf(ac[k].x,h.x,bc4[k].x); h.y = fmaf(ac[k].y,h.y,bc4[k].y);
        h.z = fmaf(ac[k].z,h.z,bc4[k].z); h.w = fmaf(ac[k].w,h.w,bc4[k].w);
    }
}

// ============ scan pass 3: re-scan + gate math (fast sigmoid); z over v ====
template<int CT>
__global__ __launch_bounds__(128)
void scan_apply8(const unsigned short* __restrict__ fp, const unsigned short* __restrict__ ip,
                 const unsigned short* __restrict__ op, const unsigned short* __restrict__ ga,
                 unsigned short* __restrict__ vz,
                 const float* __restrict__ bg, const float* __restrict__ app,
                 const float* __restrict__ cin)
{
    int hh = (blockIdx.x * 128 + threadIdx.x) * 8;
    int c = blockIdx.y, b = blockIdx.z;
    const float ap = fmaxf(app[0], 0.f);
    const bool ap1 = (ap == 1.0f);
    float bf[8], bi[8], bo[8];
#pragma unroll
    for (int j = 0; j < 8; ++j) {
        bf[j] = bg[hh+j]; bi[j] = bg[H_+hh+j]; bo[j] = bg[2*H_+hh+j];
    }
    size_t base = ((size_t)b*T_ + (size_t)c*CT)*H_ + hh;
    size_t ci = ((size_t)b*gridDim.y + c)*H_ + hh;
    float h[8];
    {
        float4 h0 = *(const float4*)(cin+ci), h1 = *(const float4*)(cin+ci+4);
        h[0]=h0.x; h[1]=h0.y; h[2]=h0.z; h[3]=h0.w;
        h[4]=h1.x; h[5]=h1.y; h[6]=h1.z; h[7]=h1.w;
    }
#pragma unroll 4
    for (int t = 0; t < CT; ++t) {
        float f[8], i8a[8], o8[8], g[8], v[8], zo[8];
        up8(*(const uint4*)(fp+base), f);
        up8(*(const uint4*)(ip+base), i8a);
        up8(*(const uint4*)(op+base), o8);
        up8(*(const uint4*)(ga+base), g);
        up8(*(const uint4*)(vz+base), v);
#pragma unroll
        for (int j=0;j<8;++j) {
            float s = fsig(-(f[j]+bf[j]));
            float a = ap1 ? s : powf(s, ap);
            float xin = fsig(i8a[j]+bi[j]) * v[j];
            h[j] = fmaf(a, h[j], xin);
            float so = fsig(o8[j]+bo[j]);
            float ge = 0.5f*g[j]*(1.f+erff(g[j]*0.70710678118654752f));
            zo[j] = ge * so * h[j];
        }
        uint4 o;
        o.x = pk2(zo[0],zo[1]); o.y = pk2(zo[2],zo[3]);
        o.z = pk2(zo[4],zo[5]); o.w = pk2(zo[6],zo[7]);
        *(uint4*)(vz + base) = o;
        base += H_;
    }
}

__global__ void zero_out(float* __restrict__ out, size_t n)
{
    for (size_t i = (size_t)blockIdx.x*256 + threadIdx.x; i < n; i += (size_t)gridDim.x*256)
        out[i] = 0.f;
}

extern "C" void kernel_launch(void* const* d_in, const int* in_sizes, int n_in,
                              void* d_out, int out_size, void* d_ws, size_t ws_size,
                              hipStream_t stream)
{
    const float* x       = (const float*)d_in[0];
    const float* W_in    = (const float*)d_in[1];
    const float* W_conv  = (const float*)d_in[2];
    const float* b_conv  = (const float*)d_in[3];
    const float* W_gates = (const float*)d_in[4];
    const float* b_gates = (const float*)d_in[5];
    const float* W_out   = (const float*)d_in[6];
    const float* alpha_p = (const float*)d_in[7];
    float* out = (float*)d_out;

    const size_t plane = (size_t)B_ * T_ * H_;   // 16.78M elems
    unsigned short* gate = (unsigned short*)d_ws;
    unsigned short* fpl  = gate + plane;   // u during GEMM1/conv, then raw f
    unsigned short* v    = fpl + plane;    // v, then z in place
    unsigned short* ipl  = v + plane;
    unsigned short* opl  = ipl + plane;
    char* R = (char*)(opl + plane);        // time-shared region

    const size_t x_elems  = (size_t)B_*T_*D_;
    const size_t wg_elems = (size_t)3*H_*H_;
    const size_t wi_elems = (size_t)2*H_*D_;
    const size_t wo_elems = (size_t)D_*H_;
    const int NCF = 128;                              // CT=16, CPL=8
    const size_t carry_b = 3*(size_t)B_*NCF*H_*4;     // 12.58 MB
    const size_t Rneed = x_elems*2 > carry_b + wo_elems*2 ? x_elems*2 : carry_b + wo_elems*2;
    const size_t need_fast = 5*plane*2 + Rneed;

    if (ws_size >= need_fast && (size_t)out_size*4 >= (wg_elems + wi_elems)*2) {
        // ---------- fast path ----------
        unsigned short* wgb  = (unsigned short*)d_out;      // dead before GEMM3 writes out
        unsigned short* winb = wgb + wg_elems;
        unsigned short* xb   = (unsigned short*)R;          // live through GEMM1
        float* cAp  = (float*)R;                            // written after GEMM1
        float* cBp  = cAp + (size_t)B_*NCF*H_;
        float* cinp = cBp + (size_t)B_*NCF*H_;
        unsigned short* woutb = (unsigned short*)(cinp + (size_t)B_*NCF*H_);

        const unsigned nx = (unsigned)(x_elems/8), nwi = (unsigned)(wi_elems/8),
                       nwg = (unsigned)(wg_elems/8), nwo = (unsigned)(wo_elems/8),
                       ncv = (unsigned)(plane/8);
        cvt3<<<(nx+nwi+nwg)/256, 256, 0, stream>>>(x, xb, nx, W_in, winb, nwi, W_gates, wgb, nwg);
        // GEMM1: gate|u = x @ W_in^T
        mgemm<1,1,1><<<dim3(32,64), 256, 0, stream>>>(
            xb, D_, winb, D_, 2*H_, gate, fpl, nullptr, nullptr);
        // conv: u -> v, fused with W_out cvt (xb dead after GEMM1)
        conv_cvt<<<(ncv+nwo)/256, 256, 0, stream>>>(fpl, W_conv, b_conv, v, ncv, W_out, woutb, nwo);
        // GEMM2: raw f|i|o = v @ W_gates^T
        mgemm<1,1,2><<<dim3(48,64), 256, 0, stream>>>(
            v, H_, wgb, H_, 3*H_, fpl, ipl, opl, nullptr);
        scan_chunk8<16><<<dim3(2,NCF,B_), 128, 0, stream>>>(fpl, ipl, v, b_gates, alpha_p, cAp, cBp);
        scan_carry16<8><<<(B_*(H_/4)*16)/256, 256, 0, stream>>>(cAp, cBp, cinp);
        scan_apply8<16><<<dim3(2,NCF,B_), 128, 0, stream>>>(fpl, ipl, opl, gate, v, b_gates, alpha_p, cinp);
        // GEMM3: out = z @ W_out^T
        mgemm<1,1,0><<<dim3(8,64), 256, 0, stream>>>(
            v, H_, woutb, H_, D_, nullptr, nullptr, nullptr, out);
        return;
    }

    // ---------- fallback (fp32 sources reg-staged; NC=16) ----------
    float* cAp = (float*)R;
    if (ws_size < 5*plane*2 + 3*(size_t)B_*16*H_*4) {
        zero_out<<<2048, 256, 0, stream>>>(out, (size_t)out_size);
        return;
    }
    const int NC = 16;   // CT = 128, CPL = 1
    float* cBp  = cAp + (size_t)B_*NC*H_;
    float* cinp = cBp + (size_t)B_*NC*H_;

    mgemm<0,0,1><<<dim3(32,64), 256, 0, stream>>>(
        x, D_, W_in, D_, 2*H_, gate, fpl, nullptr, nullptr);
    conv_cvt<<<(unsigned)(plane/8/256), 256, 0, stream>>>(fpl, W_conv, b_conv, v,
        (unsigned)(plane/8), nullptr, nullptr, 0);
    mgemm<1,0,2><<<dim3(48,64), 256, 0, stream>>>(
        v, H_, W_gates, H_, 3*H_, fpl, ipl, opl, nullptr);
    scan_chunk8<128><<<dim3(2,NC,B_), 128, 0, stream>>>(fpl, ipl, v, b_gates, alpha_p, cAp, cBp);
    scan_carry16<1><<<(B_*(H_/4)*16)/256, 256, 0, stream>>>(cAp, cBp, cinp);
    scan_apply8<128><<<dim3(2,NC,B_), 128, 0, stream>>>(fpl, ipl, opl, gate, v, b_gates, alpha_p, cinp);
    mgemm<1,0,0><<<dim3(8,64), 256, 0, stream>>>(
        v, H_, W_out, H_, D_, nullptr, nullptr, nullptr, out);
}